// Round 14
// baseline (188.563 us; speedup 1.0000x reference)
//
#include <hip/hip_runtime.h>
#include <math.h>

#define S_ 64
#define N_ 256
#define L_ 32
#define D_ 128
#define LID_ 256
#define K1_ 17
#define CH_ 32    // objects per main block
#define NW_ 8     // waves per main block

typedef __attribute__((ext_vector_type(8))) short short8;
typedef __attribute__((ext_vector_type(4))) float f32x4;

__device__ __forceinline__ unsigned short f2bf(float f) {
  unsigned int u = __float_as_uint(f);
  u += 0x7fffu + ((u >> 16) & 1u);
  return (unsigned short)(u >> 16);
}
// NOTE (round-12 postmortem): do NOT use inline-asm v_cvt_pk_bf16_f32 here.
// Each asm stmt is a scheduling barrier; 20/iter collapsed ILP (VGPR 128->80,
// VALUBusy 40->19%, main 74->137us). Manual f2bf lets the scheduler overlap.

// K-slot permutations (MFMA K-axis is order-agnostic as long as A and B agree):
// lang tokens: slot(t) = 8*((t&15)>>2) + 4*(t>>4) + (t&3)
// rel hidden : slot(h) = 32*(h>>5) + 8*((h&15)>>2) + 4*((h>>4)&1) + (h&3)

// ---------------------------------------------------------------- weight prep
__global__ __launch_bounds__(256) void tar_prep_kernel(
    const float* __restrict__ rw1, const float* __restrict__ rb1,
    const float* __restrict__ rw2, const float* __restrict__ fw1,
    const float* __restrict__ fw2, const float* __restrict__ lw1,
    const float* __restrict__ lw2, unsigned short* __restrict__ w1T,
    unsigned short* __restrict__ w2T, unsigned short* __restrict__ fw1T,
    unsigned short* __restrict__ fw2T, unsigned short* __restrict__ lw1T,
    unsigned short* __restrict__ lw2T) {
  int t = blockIdx.x * 256 + threadIdx.x;  // 0..32767
  {
    int k = t >> 7, n = t & 127;  // k 0..255 (lang layer1 K=256)
    lw1T[(size_t)n * 256 + k] = f2bf(lw1[(size_t)k * 128 + n]);
  }
  if (t < 16384) {
    int k = t >> 7, n = t & 127;
    int slot =
        32 * (k >> 5) + 8 * ((k & 15) >> 2) + 4 * ((k >> 4) & 1) + (k & 3);
    w2T[(size_t)n * 128 + slot] = f2bf(rw2[(size_t)k * 128 + n]);
    fw1T[(size_t)n * 128 + k] = f2bf(fw1[(size_t)k * 128 + n]);
    fw2T[(size_t)n * 128 + k] = f2bf(fw2[(size_t)k * 128 + n]);
    lw2T[(size_t)n * 128 + k] = f2bf(lw2[(size_t)k * 128 + n]);
  }
  if (t < 2048) {
    int n2 = t >> 4, k2 = t & 15;
    unsigned short v = 0;
    if (k2 < 10) v = f2bf(rw1[(size_t)k2 * 128 + n2]);
    else if (k2 == 10) v = f2bf(rb1[n2]);  // bias slot (rel10 slot10 == 1.0)
    w1T[(size_t)n2 * 16 + k2] = v;
  }
}

// ---------------------------------------------------------------- fused prologue
// roles: [0,1024) knn | [1024,1056) lang MLP (MFMA) | [1056,1312) feat MLP
#define KNN_NB 1024
#define LANG_NB 32
#define FM_NB 256
__global__ __launch_bounds__(256, 4) void tar_prologue(
    const float* __restrict__ coord, int* __restrict__ idx_out,
    const float* __restrict__ lx, const unsigned short* __restrict__ lw1T,
    const float* __restrict__ lb1, const unsigned short* __restrict__ lw2T,
    const float* __restrict__ lb2, unsigned short* __restrict__ lang_bf,
    unsigned short* __restrict__ langT_bf, const float* __restrict__ fx,
    const unsigned short* __restrict__ fw1T, const float* __restrict__ fb1,
    const unsigned short* __restrict__ fw2T, const float* __restrict__ fb2,
    float* __restrict__ f_out, unsigned short* __restrict__ f_bf) {
  __shared__ __align__(16) char uarena[51200];
  int bid = blockIdx.x;
  int tid = threadIdx.x;

  if (bid < KNN_NB) {
    // ---- KNN: 16 lanes/object, 4 objects/wave, u32-key selection,
    //      4-level lex butterfly (lower-index tie-break == lax.top_k)
    int wv = tid >> 6, l = tid & 63, grp = l >> 4, ln16 = l & 15;
    int obj = bid * 16 + wv * 4 + grp;  // 0..16383
    int s = obj >> 8, n = obj & 255;
    const float* cs = coord + (size_t)s * N_ * 3;
    float cx = cs[n * 3 + 0], cy = cs[n * 3 + 1], cz = cs[n * 3 + 2];
    unsigned kd[16];
#pragma unroll
    for (int q = 0; q < 16; ++q) {
      int j = ln16 + q * 16;
      float dx = cs[j * 3 + 0] - cx;
      float dy = cs[j * 3 + 1] - cy;
      float dz = cs[j * 3 + 2] - cz;
      kd[q] = __float_as_uint(dx * dx + dy * dy + dz * dz);
    }
    for (int k = 0; k < K1_; ++k) {
      unsigned m = kd[0];
#pragma unroll
      for (int q = 1; q < 16; ++q) m = min(m, kd[q]);
      int bq = 0;
#pragma unroll
      for (int q = 15; q >= 0; --q)
        if (kd[q] == m) bq = q;  // lowest q on tie -> lowest j
      int bj = ln16 + bq * 16;
      unsigned bm = m;
#pragma unroll
      for (int off = 1; off <= 8; off <<= 1) {
        unsigned om = __shfl_xor(bm, off);
        int oj = __shfl_xor(bj, off);
        if (om < bm || (om == bm && oj < bj)) { bm = om; bj = oj; }
      }
#pragma unroll
      for (int q = 0; q < 16; ++q)
        if (ln16 + q * 16 == bj) kd[q] = 0xFFFFFFFFu;
      if (ln16 == 0) idx_out[(size_t)obj * K1_ + k] = bj;
    }
  } else if (bid < KNN_NB + LANG_NB) {
    // ---- lang MLP via MFMA: 64 rows/block, K=256 layer1
    unsigned short* x_s = (unsigned short*)uarena;            // [64][264]
    unsigned short* h_s = (unsigned short*)(uarena + 33792);  // 4x[16][136]
    int base = (bid - KNN_NB) * 64;
    int w = tid >> 6, l = tid & 63, g = l >> 4, ln = l & 15;
    for (int i = tid; i < 64 * 64; i += 256) {
      int row = i >> 6, c4 = (i & 63) * 4;
      float4 v = *(const float4*)&lx[(size_t)(base + row) * LID_ + c4];
      unsigned short* dst = &x_s[row * 264 + c4];
      dst[0] = f2bf(v.x); dst[1] = f2bf(v.y);
      dst[2] = f2bf(v.z); dst[3] = f2bf(v.w);
    }
    __syncthreads();
    float b1v[8], b2v[8];
#pragma unroll
    for (int nt = 0; nt < 8; ++nt) {
      b1v[nt] = lb1[nt * 16 + ln];
      b2v[nt] = lb2[nt * 16 + ln];
    }
    short8 a1[8];
#pragma unroll
    for (int kk = 0; kk < 8; ++kk)
      a1[kk] = *(const short8*)&x_s[(w * 16 + ln) * 264 + kk * 32 + g * 8];
    unsigned short* hw = &h_s[w * 16 * 136];
#pragma unroll
    for (int nt = 0; nt < 8; ++nt) {
      f32x4 acc = {b1v[nt], b1v[nt], b1v[nt], b1v[nt]};
#pragma unroll
      for (int kk = 0; kk < 8; ++kk) {
        short8 bw =
            *(const short8*)&lw1T[(size_t)(nt * 16 + ln) * 256 + kk * 32 + g * 8];
        acc = __builtin_amdgcn_mfma_f32_16x16x32_bf16(a1[kk], bw, acc, 0, 0, 0);
      }
#pragma unroll
      for (int reg = 0; reg < 4; ++reg)
        hw[(g * 4 + reg) * 136 + nt * 16 + ln] = f2bf(fmaxf(acc[reg], 0.f));
    }
    short8 a2[4];
#pragma unroll
    for (int kk = 0; kk < 4; ++kk)
      a2[kk] = *(const short8*)&hw[ln * 136 + kk * 32 + g * 8];
#pragma unroll
    for (int nt = 0; nt < 8; ++nt) {
      f32x4 acc = {b2v[nt], b2v[nt], b2v[nt], b2v[nt]};
#pragma unroll
      for (int kk = 0; kk < 4; ++kk) {
        short8 bw =
            *(const short8*)&lw2T[(size_t)(nt * 16 + ln) * 128 + kk * 32 + g * 8];
        acc = __builtin_amdgcn_mfma_f32_16x16x32_bf16(a2[kk], bw, acc, 0, 0, 0);
      }
#pragma unroll
      for (int reg = 0; reg < 4; ++reg) {
        int row = base + w * 16 + g * 4 + reg;
        int col = nt * 16 + ln;
        unsigned short hb = f2bf(acc[reg]);
        lang_bf[(size_t)row * D_ + col] = hb;
        int s = row >> 5, t = row & 31;
        int slot = 8 * ((t & 15) >> 2) + 4 * (t >> 4) + (t & 3);
        langT_bf[((size_t)s * D_ + col) * L_ + slot] = hb;
      }
    }
  } else {
    // ---- feat MLP (MFMA), 64 rows/block
    unsigned short* x_s = (unsigned short*)uarena;            // [64][136]
    unsigned short* h_s = (unsigned short*)(uarena + 17408);  // 4x[16][136]
    int base = (bid - KNN_NB - LANG_NB) * 64;
    int w = tid >> 6, l = tid & 63, g = l >> 4, ln = l & 15;
    for (int i = tid; i < 64 * 32; i += 256) {
      int row = i >> 5, c4 = (i & 31) * 4;
      float4 v = *(const float4*)&fx[(size_t)(base + row) * D_ + c4];
      unsigned short* dst = &x_s[row * 136 + c4];
      dst[0] = f2bf(v.x); dst[1] = f2bf(v.y);
      dst[2] = f2bf(v.z); dst[3] = f2bf(v.w);
    }
    __syncthreads();
    float b1v[8], b2v[8];
#pragma unroll
    for (int nt = 0; nt < 8; ++nt) {
      b1v[nt] = fb1[nt * 16 + ln];
      b2v[nt] = fb2[nt * 16 + ln];
    }
    short8 a1[4];
#pragma unroll
    for (int kk = 0; kk < 4; ++kk)
      a1[kk] = *(const short8*)&x_s[(w * 16 + ln) * 136 + kk * 32 + g * 8];
    unsigned short* hw = &h_s[w * 16 * 136];
#pragma unroll
    for (int nt = 0; nt < 8; ++nt) {
      f32x4 acc = {b1v[nt], b1v[nt], b1v[nt], b1v[nt]};
#pragma unroll
      for (int kk = 0; kk < 4; ++kk) {
        short8 bw =
            *(const short8*)&fw1T[(size_t)(nt * 16 + ln) * 128 + kk * 32 + g * 8];
        acc = __builtin_amdgcn_mfma_f32_16x16x32_bf16(a1[kk], bw, acc, 0, 0, 0);
      }
#pragma unroll
      for (int reg = 0; reg < 4; ++reg)
        hw[(g * 4 + reg) * 136 + nt * 16 + ln] = f2bf(fmaxf(acc[reg], 0.f));
    }
    short8 a2[4];
#pragma unroll
    for (int kk = 0; kk < 4; ++kk)
      a2[kk] = *(const short8*)&hw[ln * 136 + kk * 32 + g * 8];
#pragma unroll
    for (int nt = 0; nt < 8; ++nt) {
      f32x4 acc = {b2v[nt], b2v[nt], b2v[nt], b2v[nt]};
#pragma unroll
      for (int kk = 0; kk < 4; ++kk) {
        short8 bw =
            *(const short8*)&fw2T[(size_t)(nt * 16 + ln) * 128 + kk * 32 + g * 8];
        acc = __builtin_amdgcn_mfma_f32_16x16x32_bf16(a2[kk], bw, acc, 0, 0, 0);
      }
#pragma unroll
      for (int reg = 0; reg < 4; ++reg) {
        int row = base + w * 16 + g * 4 + reg;
        int col = nt * 16 + ln;
        f_out[(size_t)row * D_ + col] = acc[reg];
        f_bf[(size_t)row * D_ + col] = f2bf(acc[reg]);
      }
    }
  }
}

// ---------------------------------------------------------------- main MFMA
// block = (sentence, 32 objects), 8 waves = (og, q): og = 16-obj group,
// q = k mod 4 (k = q, q+4, ...). DE-DUPLICATED vs round 13: each k's
// G3+softmax+G1+packs now computed ONCE (was twice across the h-pair);
// each wave owns all 8 nt output tiles (o[8] = 32 VGPRs -- fits the
// 128-VGPR cap that (512,2) provides; the round-4 spill was under a
// 64-VGPR allocation). Per block: MFMA 2448->1904, VALU ~-35%.
// w2T from GLOBAL (round 11), no inline asm (round 12).
__global__ __launch_bounds__(512, 2) void tar_main_mfma(
    const float* __restrict__ f_out, const unsigned short* __restrict__ f_bf,
    const unsigned short* __restrict__ lang_bf,
    const unsigned short* __restrict__ langT_bf, const int* __restrict__ idxg,
    const float* __restrict__ coord, const unsigned short* __restrict__ w1T_bf,
    const unsigned short* __restrict__ w2T_bf, const float* __restrict__ rel_b2,
    const int* __restrict__ lang_len, float* __restrict__ outp,
    float* __restrict__ score) {
  // staging: lang_s [32][136]u16 @0 (8704) | langT_s [128][40]u16 @8704
  //          (10240) | w1T_s [128][24]u16 @18944 (6144) | idx_s @25088 (2176)
  //          = 27264 B; epilogue aliases arena as R = 8x[128][16] f32 (65536)
  __shared__ __align__(16) char arena[65536];
  __shared__ float score_s[CH_];

  unsigned short* lang_s = (unsigned short*)(arena);
  unsigned short* langT_s = (unsigned short*)(arena + 8704);
  unsigned short* w1T_s = (unsigned short*)(arena + 18944);
  int* idx_s = (int*)(arena + 25088);

  int b = blockIdx.x;
  int s = b >> 3;
  int chunk = b & 7;
  int sn0 = s * N_ + chunk * CH_;
  int tid = threadIdx.x;
  int w = tid >> 6;
  int l = tid & 63;
  int g = l >> 4;
  int ln = l & 15;
  int og = w >> 2;  // object group (0/1)
  int q = w & 3;    // k stride lane: k = q, q+4, ...
  int len = lang_len[s];

  {
    int row = tid >> 4, c0 = (tid & 15) * 8;
    *(short8*)&lang_s[row * 136 + c0] =
        *(const short8*)&lang_bf[((size_t)s * L_ + row) * D_ + c0];
  }
  {
    int row = tid >> 2, c0 = (tid & 3) * 8;
    *(short8*)&langT_s[row * 40 + c0] =
        *(const short8*)&langT_bf[((size_t)s * D_ + row) * L_ + c0];
  }
  if (tid < 256) {
    int row = tid >> 1, c0 = (tid & 1) * 8;
    *(short8*)&w1T_s[row * 24 + c0] =
        *(const short8*)&w1T_bf[(size_t)row * 16 + c0];
  }
  for (int i = tid; i < CH_ * K1_; i += 512)
    idx_s[i] = idxg[(size_t)sn0 * K1_ + i];
  if (tid < CH_) score_s[tid] = 0.f;
  __syncthreads();

  float b2v[8];
#pragma unroll
  for (int nt = 0; nt < 8; ++nt) b2v[nt] = rel_b2[nt * 16 + ln];

  f32x4 o[8];
#pragma unroll
  for (int nt = 0; nt < 8; ++nt) o[nt] = (f32x4){0.f, 0.f, 0.f, 0.f};

  int objA = og * 16 + ln;  // this lane's obj (B-row / column owner)
  const float* fbase = &f_out[(size_t)s * N_ * D_];
  const float* cA = coord + (size_t)(sn0 + objA) * 3;
  float cx = cA[0], cy = cA[1], cz = cA[2];

  for (int k = q; k < K1_; k += 4) {
    int nbrA = idx_s[objA * K1_ + k];
    int nbrC[4];
#pragma unroll
    for (int reg = 0; reg < 4; ++reg)
      nbrC[reg] = idx_s[(og * 16 + g * 4 + reg) * K1_ + k];

    // ---- rel10 inline from coords (issued early; hides under G3)
    const float* cN = coord + (size_t)(s * N_ + nbrA) * 3;
    float nx = cN[0], ny = cN[1], nz = cN[2];
    float rx = nx - cx, ry = ny - cy, rz = nz - cz;
    float dist = sqrtf(rx * rx + ry * ry + rz * rz);
    short8 a1v = {0, 0, 0, 0, 0, 0, 0, 0};
    if (g == 0) {
      a1v[0] = (short)f2bf(nx); a1v[1] = (short)f2bf(ny);
      a1v[2] = (short)f2bf(nz); a1v[3] = (short)f2bf(cx);
      a1v[4] = (short)f2bf(cy); a1v[5] = (short)f2bf(cz);
      a1v[6] = (short)f2bf(rx); a1v[7] = (short)f2bf(ry);
    } else if (g == 1) {
      a1v[0] = (short)f2bf(rz);
      a1v[1] = (short)f2bf(dist);
      a1v[2] = (short)0x3F80;  // 1.0 -> bias slot 10
    }

    const unsigned short* fArow = &f_bf[((size_t)s * N_ + nbrA) * D_];

    // ---- G3 swapped: at = lang @ f_nb^T -> C[token][obj], obj = ln
    f32x4 at0 = {0.f, 0.f, 0.f, 0.f}, at1 = {0.f, 0.f, 0.f, 0.f};
#pragma unroll
    for (int kk = 0; kk < 4; ++kk) {
      short8 fA = *(const short8*)&fArow[kk * 32 + g * 8];
      short8 bb0 = *(const short8*)&lang_s[ln * 136 + kk * 32 + g * 8];
      short8 bb1 = *(const short8*)&lang_s[(16 + ln) * 136 + kk * 32 + g * 8];
      at0 = __builtin_amdgcn_mfma_f32_16x16x32_bf16(bb0, fA, at0, 0, 0, 0);
      at1 = __builtin_amdgcn_mfma_f32_16x16x32_bf16(bb1, fA, at1, 0, 0, 0);
    }

    // ---- softmax for obj ln: tokens at0->4g+reg, at1->16+4g+reg.
    //      local over 8 + shfl_xor(16,32). ref-exact algebra.
    float mx = fmaxf(fmaxf(fmaxf(at0[0], at0[1]), fmaxf(at0[2], at0[3])),
                     fmaxf(fmaxf(at1[0], at1[1]), fmaxf(at1[2], at1[3])));
    mx = fmaxf(mx, __shfl_xor(mx, 16));
    mx = fmaxf(mx, __shfl_xor(mx, 32));
    float e0[4], e1[4], p0[4], p1[4];
    float ss = 0.f, ms = 0.f;
#pragma unroll
    for (int reg = 0; reg < 4; ++reg) {
      e0[reg] = expf(at0[reg] - mx);
      e1[reg] = expf(at1[reg] - mx);
      ss += e0[reg] + e1[reg];
      p0[reg] = (4 * g + reg < len) ? e0[reg] : 0.f;
      p1[reg] = (16 + 4 * g + reg < len) ? e1[reg] : 0.f;
      ms += p0[reg] + p1[reg];
    }
    ss += __shfl_xor(ss, 16);
    ss += __shfl_xor(ss, 32);
    ms += __shfl_xor(ms, 16);
    ms += __shfl_xor(ms, 32);
    float inv = 1.0f / (ms + 1e-7f * ss);  // == q/ssum / (ms/ssum + 1e-7)
    short8 pa;
#pragma unroll
    for (int reg = 0; reg < 4; ++reg) {
      pa[reg] = (short)f2bf(p0[reg] * inv);
      pa[4 + reg] = (short)f2bf(p1[reg] * inv);
    }

    // ---- G1 swapped: relh = w1T-chunks @ rel10 -> C[h][obj], obj = ln.
    //      relu + pack to a2 (K-slot perm matches w2T prep).
    short8 a2[4];
#pragma unroll
    for (int kk = 0; kk < 4; ++kk) {
      short8 bw0 = {0, 0, 0, 0, 0, 0, 0, 0};
      short8 bw1 = {0, 0, 0, 0, 0, 0, 0, 0};
      if (g < 2) {
        bw0 = *(const short8*)&w1T_s[((2 * kk) * 16 + ln) * 24 + g * 8];
        bw1 = *(const short8*)&w1T_s[((2 * kk + 1) * 16 + ln) * 24 + g * 8];
      }
      f32x4 z = {0.f, 0.f, 0.f, 0.f};
      f32x4 r0 = __builtin_amdgcn_mfma_f32_16x16x32_bf16(bw0, a1v, z, 0, 0, 0);
      f32x4 r1 = __builtin_amdgcn_mfma_f32_16x16x32_bf16(bw1, a1v, z, 0, 0, 0);
#pragma unroll
      for (int reg = 0; reg < 4; ++reg) {
        a2[kk][reg] = (short)f2bf(fmaxf(r0[reg], 0.f));
        a2[kk][4 + reg] = (short)f2bf(fmaxf(r1[reg], 0.f));
      }
    }

    // ---- per-nt: G2 (a2 @ w2T global) + G4 (pa @ langT_s) + combine,
    //      all 8 col-tiles (dedup: this wave owns the whole row strip)
#pragma unroll
    for (int nt = 0; nt < 8; ++nt) {
      f32x4 ro = {b2v[nt], b2v[nt], b2v[nt], b2v[nt]};
#pragma unroll
      for (int kk = 0; kk < 4; ++kk) {
        short8 bw =
            *(const short8*)&w2T_bf[(size_t)(nt * 16 + ln) * 128 + kk * 32 + g * 8];
        ro = __builtin_amdgcn_mfma_f32_16x16x32_bf16(a2[kk], bw, ro, 0, 0, 0);
      }
      f32x4 iv = {0.f, 0.f, 0.f, 0.f};
      short8 bl = *(const short8*)&langT_s[(nt * 16 + ln) * 40 + g * 8];
      iv = __builtin_amdgcn_mfma_f32_16x16x32_bf16(pa, bl, iv, 0, 0, 0);
#pragma unroll
      for (int reg = 0; reg < 4; ++reg) {
        float fv = fbase[(size_t)nbrC[reg] * D_ + nt * 16 + ln];
        o[nt][reg] += fv * iv[reg] * ro[reg];
      }
    }
  }

  // ---- cross-wave reduction (4 waves per object group) ----
  __syncthreads();  // all tile work done; arena free for reuse
  float* R = (float*)arena;  // 8 waves x [128 cols][16 rows] f32
  {
    float* Rw = R + w * 2048;
#pragma unroll
    for (int nt = 0; nt < 8; ++nt)
      *(f32x4*)&Rw[(nt * 16 + ln) * 16 + g * 4] = o[nt];
  }
  __syncthreads();
  {
    float vs[2][4];
#pragma unroll
    for (int t = 0; t < 2; ++t) {
      int nt = q * 2 + t;
      int col = nt * 16 + ln;
      f32x4 sum = {0.f, 0.f, 0.f, 0.f};
#pragma unroll
      for (int w2 = 0; w2 < 4; ++w2)
        sum += *(f32x4*)&R[(og * 4 + w2) * 2048 + col * 16 + g * 4];
#pragma unroll
      for (int reg = 0; reg < 4; ++reg) {
        int obj = og * 16 + g * 4 + reg;
        float v = sum[reg] + f_out[(size_t)(sn0 + obj) * D_ + col];
        outp[(size_t)(sn0 + obj) * D_ + col] = v;
        vs[t][reg] = v;
      }
    }
#pragma unroll
    for (int reg = 0; reg < 4; ++reg) {
      float sv = vs[0][reg] + vs[1][reg];
      sv += __shfl_xor(sv, 1);
      sv += __shfl_xor(sv, 2);
      sv += __shfl_xor(sv, 4);
      sv += __shfl_xor(sv, 8);
      if (ln == 0) atomicAdd(&score_s[og * 16 + g * 4 + reg], sv);
    }
  }
  __syncthreads();
  if (tid < CH_) score[sn0 + tid] = score_s[tid];
}

extern "C" void kernel_launch(void* const* d_in, const int* in_sizes, int n_in,
                              void* d_out, int out_size, void* d_ws,
                              size_t ws_size, hipStream_t stream) {
  const float* feat = (const float*)d_in[0];
  const float* coord = (const float*)d_in[1];
  const float* lang_feat = (const float*)d_in[2];
  const int* lang_len = (const int*)d_in[3];
  const float* rel_w1 = (const float*)d_in[4];
  const float* rel_b1 = (const float*)d_in[5];
  const float* rel_w2 = (const float*)d_in[6];
  const float* rel_b2 = (const float*)d_in[7];
  const float* lang_w1 = (const float*)d_in[8];
  const float* lang_b1 = (const float*)d_in[9];
  const float* lang_w2 = (const float*)d_in[10];
  const float* lang_b2 = (const float*)d_in[11];
  const float* feat_w1 = (const float*)d_in[12];
  const float* feat_b1 = (const float*)d_in[13];
  const float* feat_w2 = (const float*)d_in[14];
  const float* feat_b2 = (const float*)d_in[15];

  char* ws = (char*)d_ws;
  unsigned short* lang_bf = (unsigned short*)(ws);                  // 512 KB
  unsigned short* langT_bf = (unsigned short*)(ws + 524288);        // 512 KB
  float* f_out = (float*)(ws + 1048576);                            // 8 MB
  unsigned short* f_bf = (unsigned short*)(ws + 9437184);           // 4 MB
  int* idx = (int*)(ws + 13631488);                                 // ~1.1 MB
  unsigned short* w2T_bf = (unsigned short*)(ws + 14745600);        // 32 KB
  unsigned short* w1T_bf = (unsigned short*)(ws + 14778368);        // 4 KB
  unsigned short* fw1T_bf = (unsigned short*)(ws + 14782464);       // 32 KB
  unsigned short* fw2T_bf = (unsigned short*)(ws + 14815232);       // 32 KB
  unsigned short* lw1T_bf = (unsigned short*)(ws + 14848000);       // 64 KB
  unsigned short* lw2T_bf = (unsigned short*)(ws + 14913536);       // 32 KB

  float* out = (float*)d_out;
  float* score = out + (size_t)S_ * N_ * D_;

  tar_prep_kernel<<<dim3(128), dim3(256), 0, stream>>>(
      rel_w1, rel_b1, rel_w2, feat_w1, feat_w2, lang_w1, lang_w2, w1T_bf,
      w2T_bf, fw1T_bf, fw2T_bf, lw1T_bf, lw2T_bf);
  tar_prologue<<<dim3(KNN_NB + LANG_NB + FM_NB), dim3(256), 0, stream>>>(
      coord, idx, lang_feat, lw1T_bf, lang_b1, lw2T_bf, lang_b2, lang_bf,
      langT_bf, feat, fw1T_bf, feat_b1, fw2T_bf, feat_b2, f_out, f_bf);
  tar_main_mfma<<<dim3(S_ * (N_ / CH_)), dim3(512), 0, stream>>>(
      f_out, f_bf, lang_bf, langT_bf, idx, coord, w1T_bf, w2T_bf, rel_b2,
      lang_len, out, score);
}

// Round 15
// 147.520 us; speedup vs baseline: 1.2782x; 1.2782x over previous
//
#include <hip/hip_runtime.h>
#include <math.h>

#define S_ 64
#define N_ 256
#define L_ 32
#define D_ 128
#define LID_ 256
#define K1_ 17
#define CH_ 32    // objects per main block
#define NW_ 8     // waves per main block

typedef __attribute__((ext_vector_type(8))) short short8;
typedef __attribute__((ext_vector_type(4))) float f32x4;

__device__ __forceinline__ unsigned short f2bf(float f) {
  unsigned int u = __float_as_uint(f);
  u += 0x7fffu + ((u >> 16) & 1u);
  return (unsigned short)(u >> 16);
}
// NOTE (round-12): no inline-asm cvt_pk -- each asm stmt is a scheduler
// barrier; 20/iter collapsed ILP (main 74->137us). Manual f2bf only.
// NOTE (round-14): o[8] dedup spills at the 128-VGPR cap (WRITE 8->102MB,
// main 74->144us). Keep the h-pair duplication; it IS the register budget.

// K-slot permutations (MFMA K-axis is order-agnostic as long as A and B agree):
// lang tokens: slot(t) = 8*((t&15)>>2) + 4*(t>>4) + (t&3)
// rel hidden : slot(h) = 32*(h>>5) + 8*((h&15)>>2) + 4*((h>>4)&1) + (h&3)

// ---------------------------------------------------------------- weight prep
__global__ __launch_bounds__(256) void tar_prep_kernel(
    const float* __restrict__ rw1, const float* __restrict__ rb1,
    const float* __restrict__ rw2, const float* __restrict__ fw1,
    const float* __restrict__ fw2, const float* __restrict__ lw1,
    const float* __restrict__ lw2, unsigned short* __restrict__ w1T,
    unsigned short* __restrict__ w2T, unsigned short* __restrict__ fw1T,
    unsigned short* __restrict__ fw2T, unsigned short* __restrict__ lw1T,
    unsigned short* __restrict__ lw2T) {
  int t = blockIdx.x * 256 + threadIdx.x;  // 0..32767
  {
    int k = t >> 7, n = t & 127;  // k 0..255 (lang layer1 K=256)
    lw1T[(size_t)n * 256 + k] = f2bf(lw1[(size_t)k * 128 + n]);
  }
  if (t < 16384) {
    int k = t >> 7, n = t & 127;
    int slot =
        32 * (k >> 5) + 8 * ((k & 15) >> 2) + 4 * ((k >> 4) & 1) + (k & 3);
    w2T[(size_t)n * 128 + slot] = f2bf(rw2[(size_t)k * 128 + n]);
    fw1T[(size_t)n * 128 + k] = f2bf(fw1[(size_t)k * 128 + n]);
    fw2T[(size_t)n * 128 + k] = f2bf(fw2[(size_t)k * 128 + n]);
    lw2T[(size_t)n * 128 + k] = f2bf(lw2[(size_t)k * 128 + n]);
  }
  if (t < 2048) {
    int n2 = t >> 4, k2 = t & 15;
    unsigned short v = 0;
    if (k2 < 10) v = f2bf(rw1[(size_t)k2 * 128 + n2]);
    else if (k2 == 10) v = f2bf(rb1[n2]);  // bias slot (rel10 slot10 == 1.0)
    w1T[(size_t)n2 * 16 + k2] = v;
  }
}

// ---------------------------------------------------------------- fused prologue
// KNN moved INTO the main kernel (round 15) -- roles here are only:
// [0,32) lang MLP (MFMA) | [32,288) feat MLP (MFMA)
#define LANG_NB 32
#define FM_NB 256
__global__ __launch_bounds__(256, 4) void tar_prologue(
    const float* __restrict__ lx, const unsigned short* __restrict__ lw1T,
    const float* __restrict__ lb1, const unsigned short* __restrict__ lw2T,
    const float* __restrict__ lb2, unsigned short* __restrict__ lang_bf,
    unsigned short* __restrict__ langT_bf, const float* __restrict__ fx,
    const unsigned short* __restrict__ fw1T, const float* __restrict__ fb1,
    const unsigned short* __restrict__ fw2T, const float* __restrict__ fb2,
    float* __restrict__ f_out, unsigned short* __restrict__ f_bf) {
  __shared__ __align__(16) char uarena[51200];
  int bid = blockIdx.x;
  int tid = threadIdx.x;

  if (bid < LANG_NB) {
    // ---- lang MLP via MFMA: 64 rows/block, K=256 layer1
    unsigned short* x_s = (unsigned short*)uarena;            // [64][264]
    unsigned short* h_s = (unsigned short*)(uarena + 33792);  // 4x[16][136]
    int base = bid * 64;
    int w = tid >> 6, l = tid & 63, g = l >> 4, ln = l & 15;
    for (int i = tid; i < 64 * 64; i += 256) {
      int row = i >> 6, c4 = (i & 63) * 4;
      float4 v = *(const float4*)&lx[(size_t)(base + row) * LID_ + c4];
      unsigned short* dst = &x_s[row * 264 + c4];
      dst[0] = f2bf(v.x); dst[1] = f2bf(v.y);
      dst[2] = f2bf(v.z); dst[3] = f2bf(v.w);
    }
    __syncthreads();
    float b1v[8], b2v[8];
#pragma unroll
    for (int nt = 0; nt < 8; ++nt) {
      b1v[nt] = lb1[nt * 16 + ln];
      b2v[nt] = lb2[nt * 16 + ln];
    }
    short8 a1[8];
#pragma unroll
    for (int kk = 0; kk < 8; ++kk)
      a1[kk] = *(const short8*)&x_s[(w * 16 + ln) * 264 + kk * 32 + g * 8];
    unsigned short* hw = &h_s[w * 16 * 136];
#pragma unroll
    for (int nt = 0; nt < 8; ++nt) {
      f32x4 acc = {b1v[nt], b1v[nt], b1v[nt], b1v[nt]};
#pragma unroll
      for (int kk = 0; kk < 8; ++kk) {
        short8 bw =
            *(const short8*)&lw1T[(size_t)(nt * 16 + ln) * 256 + kk * 32 + g * 8];
        acc = __builtin_amdgcn_mfma_f32_16x16x32_bf16(a1[kk], bw, acc, 0, 0, 0);
      }
#pragma unroll
      for (int reg = 0; reg < 4; ++reg)
        hw[(g * 4 + reg) * 136 + nt * 16 + ln] = f2bf(fmaxf(acc[reg], 0.f));
    }
    short8 a2[4];
#pragma unroll
    for (int kk = 0; kk < 4; ++kk)
      a2[kk] = *(const short8*)&hw[ln * 136 + kk * 32 + g * 8];
#pragma unroll
    for (int nt = 0; nt < 8; ++nt) {
      f32x4 acc = {b2v[nt], b2v[nt], b2v[nt], b2v[nt]};
#pragma unroll
      for (int kk = 0; kk < 4; ++kk) {
        short8 bw =
            *(const short8*)&lw2T[(size_t)(nt * 16 + ln) * 128 + kk * 32 + g * 8];
        acc = __builtin_amdgcn_mfma_f32_16x16x32_bf16(a2[kk], bw, acc, 0, 0, 0);
      }
#pragma unroll
      for (int reg = 0; reg < 4; ++reg) {
        int row = base + w * 16 + g * 4 + reg;
        int col = nt * 16 + ln;
        unsigned short hb = f2bf(acc[reg]);
        lang_bf[(size_t)row * D_ + col] = hb;
        int s = row >> 5, t = row & 31;
        int slot = 8 * ((t & 15) >> 2) + 4 * (t >> 4) + (t & 3);
        langT_bf[((size_t)s * D_ + col) * L_ + slot] = hb;
      }
    }
  } else {
    // ---- feat MLP (MFMA), 64 rows/block
    unsigned short* x_s = (unsigned short*)uarena;            // [64][136]
    unsigned short* h_s = (unsigned short*)(uarena + 17408);  // 4x[16][136]
    int base = (bid - LANG_NB) * 64;
    int w = tid >> 6, l = tid & 63, g = l >> 4, ln = l & 15;
    for (int i = tid; i < 64 * 32; i += 256) {
      int row = i >> 5, c4 = (i & 31) * 4;
      float4 v = *(const float4*)&fx[(size_t)(base + row) * D_ + c4];
      unsigned short* dst = &x_s[row * 136 + c4];
      dst[0] = f2bf(v.x); dst[1] = f2bf(v.y);
      dst[2] = f2bf(v.z); dst[3] = f2bf(v.w);
    }
    __syncthreads();
    float b1v[8], b2v[8];
#pragma unroll
    for (int nt = 0; nt < 8; ++nt) {
      b1v[nt] = fb1[nt * 16 + ln];
      b2v[nt] = fb2[nt * 16 + ln];
    }
    short8 a1[4];
#pragma unroll
    for (int kk = 0; kk < 4; ++kk)
      a1[kk] = *(const short8*)&x_s[(w * 16 + ln) * 136 + kk * 32 + g * 8];
    unsigned short* hw = &h_s[w * 16 * 136];
#pragma unroll
    for (int nt = 0; nt < 8; ++nt) {
      f32x4 acc = {b1v[nt], b1v[nt], b1v[nt], b1v[nt]};
#pragma unroll
      for (int kk = 0; kk < 4; ++kk) {
        short8 bw =
            *(const short8*)&fw1T[(size_t)(nt * 16 + ln) * 128 + kk * 32 + g * 8];
        acc = __builtin_amdgcn_mfma_f32_16x16x32_bf16(a1[kk], bw, acc, 0, 0, 0);
      }
#pragma unroll
      for (int reg = 0; reg < 4; ++reg)
        hw[(g * 4 + reg) * 136 + nt * 16 + ln] = f2bf(fmaxf(acc[reg], 0.f));
    }
    short8 a2[4];
#pragma unroll
    for (int kk = 0; kk < 4; ++kk)
      a2[kk] = *(const short8*)&hw[ln * 136 + kk * 32 + g * 8];
#pragma unroll
    for (int nt = 0; nt < 8; ++nt) {
      f32x4 acc = {b2v[nt], b2v[nt], b2v[nt], b2v[nt]};
#pragma unroll
      for (int kk = 0; kk < 4; ++kk) {
        short8 bw =
            *(const short8*)&fw2T[(size_t)(nt * 16 + ln) * 128 + kk * 32 + g * 8];
        acc = __builtin_amdgcn_mfma_f32_16x16x32_bf16(a2[kk], bw, acc, 0, 0, 0);
      }
#pragma unroll
      for (int reg = 0; reg < 4; ++reg) {
        int row = base + w * 16 + g * 4 + reg;
        int col = nt * 16 + ln;
        f_out[(size_t)row * D_ + col] = acc[reg];
        f_bf[(size_t)row * D_ + col] = f2bf(acc[reg]);
      }
    }
  }
}

// ---------------------------------------------------------------- main MFMA
// block = (sentence, 32 objects), 8 waves = (og, h, q2) -- round-13 proven
// structure. NEW (round 15): KNN fused in -- each wave computes KNN for 4
// of the block's 32 objects (16 lanes/object, u32-key, lex tie-break ==
// lax.top_k) directly into idx_s, overlapping the LDS staging loads. This
// deletes 1024 prologue blocks + the idx global round-trip.
__global__ __launch_bounds__(512, 2) void tar_main_mfma(
    const float* __restrict__ f_out, const unsigned short* __restrict__ f_bf,
    const unsigned short* __restrict__ lang_bf,
    const unsigned short* __restrict__ langT_bf,
    const float* __restrict__ coord, const unsigned short* __restrict__ w1T_bf,
    const unsigned short* __restrict__ w2T_bf, const float* __restrict__ rel_b2,
    const int* __restrict__ lang_len, float* __restrict__ outp,
    float* __restrict__ score) {
  // staging: lang_s [32][136]u16 @0 (8704) | langT_s [128][40]u16 @8704
  //          (10240) | w1T_s [128][24]u16 @18944 (6144) | idx_s @25088 (2176)
  //          = 27264 B; epilogue aliases arena as R = 8x[64][20] f32 (40960)
  __shared__ __align__(16) char arena[40960];
  __shared__ float score_s[CH_];

  unsigned short* lang_s = (unsigned short*)(arena);
  unsigned short* langT_s = (unsigned short*)(arena + 8704);
  unsigned short* w1T_s = (unsigned short*)(arena + 18944);
  int* idx_s = (int*)(arena + 25088);

  int b = blockIdx.x;
  int s = b >> 3;
  int chunk = b & 7;
  int sn0 = s * N_ + chunk * CH_;
  int tid = threadIdx.x;
  int w = tid >> 6;
  int l = tid & 63;
  int g = l >> 4;
  int ln = l & 15;
  int og = w >> 2;        // object group (0/1)
  int h = (w >> 1) & 1;   // nt half: tiles h*4 .. h*4+3
  int q2 = w & 1;         // k parity
  int len = lang_len[s];

  {
    int row = tid >> 4, c0 = (tid & 15) * 8;
    *(short8*)&lang_s[row * 136 + c0] =
        *(const short8*)&lang_bf[((size_t)s * L_ + row) * D_ + c0];
  }
  {
    int row = tid >> 2, c0 = (tid & 3) * 8;
    *(short8*)&langT_s[row * 40 + c0] =
        *(const short8*)&langT_bf[((size_t)s * D_ + row) * L_ + c0];
  }
  if (tid < 256) {
    int row = tid >> 1, c0 = (tid & 1) * 8;
    *(short8*)&w1T_s[row * 24 + c0] =
        *(const short8*)&w1T_bf[(size_t)row * 16 + c0];
  }
  if (tid < CH_) score_s[tid] = 0.f;

  // ---- fused KNN: wave w owns objects w*4+g (g = lane>>4), 16 lanes each.
  //      VALU-heavy -> overlaps the staging loads issued above.
  {
    int objL = w * 4 + g;           // chunk-local object 0..31
    int n = chunk * CH_ + objL;     // sentence-local object id
    const float* cs = coord + (size_t)s * N_ * 3;
    float cx = cs[n * 3 + 0], cy = cs[n * 3 + 1], cz = cs[n * 3 + 2];
    unsigned kd[16];
#pragma unroll
    for (int q = 0; q < 16; ++q) {
      int j = ln + q * 16;
      float dx = cs[j * 3 + 0] - cx;
      float dy = cs[j * 3 + 1] - cy;
      float dz = cs[j * 3 + 2] - cz;
      kd[q] = __float_as_uint(dx * dx + dy * dy + dz * dz);
    }
    for (int k = 0; k < K1_; ++k) {
      unsigned m = kd[0];
#pragma unroll
      for (int q = 1; q < 16; ++q) m = min(m, kd[q]);
      int bq = 0;
#pragma unroll
      for (int q = 15; q >= 0; --q)
        if (kd[q] == m) bq = q;  // lowest q on tie -> lowest j
      int bj = ln + bq * 16;
      unsigned bm = m;
#pragma unroll
      for (int off = 1; off <= 8; off <<= 1) {
        unsigned om = __shfl_xor(bm, off);
        int oj = __shfl_xor(bj, off);
        if (om < bm || (om == bm && oj < bj)) { bm = om; bj = oj; }
      }
#pragma unroll
      for (int q = 0; q < 16; ++q)
        if (ln + q * 16 == bj) kd[q] = 0xFFFFFFFFu;
      if (ln == 0) idx_s[objL * K1_ + k] = bj;
    }
  }
  __syncthreads();

  float b2v[4];
#pragma unroll
  for (int j = 0; j < 4; ++j) b2v[j] = rel_b2[(h * 4 + j) * 16 + ln];

  f32x4 o[4];
#pragma unroll
  for (int j = 0; j < 4; ++j) o[j] = (f32x4){0.f, 0.f, 0.f, 0.f};

  int objA = og * 16 + ln;  // this lane's obj (B-row / column owner)
  const float* fbase = &f_out[(size_t)s * N_ * D_];
  const float* cA = coord + (size_t)(sn0 + objA) * 3;
  float cx = cA[0], cy = cA[1], cz = cA[2];

  for (int k = q2; k < K1_; k += 2) {
    int nbrA = idx_s[objA * K1_ + k];
    int nbrC[4];
#pragma unroll
    for (int reg = 0; reg < 4; ++reg)
      nbrC[reg] = idx_s[(og * 16 + g * 4 + reg) * K1_ + k];

    // ---- rel10 inline from coords (issued early; hides under G3)
    const float* cN = coord + (size_t)(s * N_ + nbrA) * 3;
    float nx = cN[0], ny = cN[1], nz = cN[2];
    float rx = nx - cx, ry = ny - cy, rz = nz - cz;
    float dist = sqrtf(rx * rx + ry * ry + rz * rz);
    short8 a1v = {0, 0, 0, 0, 0, 0, 0, 0};
    if (g == 0) {
      a1v[0] = (short)f2bf(nx); a1v[1] = (short)f2bf(ny);
      a1v[2] = (short)f2bf(nz); a1v[3] = (short)f2bf(cx);
      a1v[4] = (short)f2bf(cy); a1v[5] = (short)f2bf(cz);
      a1v[6] = (short)f2bf(rx); a1v[7] = (short)f2bf(ry);
    } else if (g == 1) {
      a1v[0] = (short)f2bf(rz);
      a1v[1] = (short)f2bf(dist);
      a1v[2] = (short)0x3F80;  // 1.0 -> bias slot 10
    }

    const unsigned short* fArow = &f_bf[((size_t)s * N_ + nbrA) * D_];

    // ---- G3 swapped: at = lang @ f_nb^T -> C[token][obj], obj = ln
    f32x4 at0 = {0.f, 0.f, 0.f, 0.f}, at1 = {0.f, 0.f, 0.f, 0.f};
#pragma unroll
    for (int kk = 0; kk < 4; ++kk) {
      short8 fA = *(const short8*)&fArow[kk * 32 + g * 8];
      short8 bb0 = *(const short8*)&lang_s[ln * 136 + kk * 32 + g * 8];
      short8 bb1 = *(const short8*)&lang_s[(16 + ln) * 136 + kk * 32 + g * 8];
      at0 = __builtin_amdgcn_mfma_f32_16x16x32_bf16(bb0, fA, at0, 0, 0, 0);
      at1 = __builtin_amdgcn_mfma_f32_16x16x32_bf16(bb1, fA, at1, 0, 0, 0);
    }

    // ---- softmax for obj ln: tokens at0->4g+reg, at1->16+4g+reg.
    //      local over 8 + shfl_xor(16,32). ref-exact algebra.
    float mx = fmaxf(fmaxf(fmaxf(at0[0], at0[1]), fmaxf(at0[2], at0[3])),
                     fmaxf(fmaxf(at1[0], at1[1]), fmaxf(at1[2], at1[3])));
    mx = fmaxf(mx, __shfl_xor(mx, 16));
    mx = fmaxf(mx, __shfl_xor(mx, 32));
    float e0[4], e1[4], p0[4], p1[4];
    float ss = 0.f, ms = 0.f;
#pragma unroll
    for (int reg = 0; reg < 4; ++reg) {
      e0[reg] = expf(at0[reg] - mx);
      e1[reg] = expf(at1[reg] - mx);
      ss += e0[reg] + e1[reg];
      p0[reg] = (4 * g + reg < len) ? e0[reg] : 0.f;
      p1[reg] = (16 + 4 * g + reg < len) ? e1[reg] : 0.f;
      ms += p0[reg] + p1[reg];
    }
    ss += __shfl_xor(ss, 16);
    ss += __shfl_xor(ss, 32);
    ms += __shfl_xor(ms, 16);
    ms += __shfl_xor(ms, 32);
    float inv = 1.0f / (ms + 1e-7f * ss);  // == q/ssum / (ms/ssum + 1e-7)
    short8 pa;
#pragma unroll
    for (int reg = 0; reg < 4; ++reg) {
      pa[reg] = (short)f2bf(p0[reg] * inv);
      pa[4 + reg] = (short)f2bf(p1[reg] * inv);
    }

    // ---- G1 swapped: relh = w1T-chunks @ rel10 -> C[h][obj], obj = ln.
    //      relu + pack to a2 (K-slot perm matches w2T prep).
    short8 a2[4];
#pragma unroll
    for (int kk = 0; kk < 4; ++kk) {
      short8 bw0 = {0, 0, 0, 0, 0, 0, 0, 0};
      short8 bw1 = {0, 0, 0, 0, 0, 0, 0, 0};
      if (g < 2) {
        bw0 = *(const short8*)&w1T_s[((2 * kk) * 16 + ln) * 24 + g * 8];
        bw1 = *(const short8*)&w1T_s[((2 * kk + 1) * 16 + ln) * 24 + g * 8];
      }
      f32x4 z = {0.f, 0.f, 0.f, 0.f};
      f32x4 r0 = __builtin_amdgcn_mfma_f32_16x16x32_bf16(bw0, a1v, z, 0, 0, 0);
      f32x4 r1 = __builtin_amdgcn_mfma_f32_16x16x32_bf16(bw1, a1v, z, 0, 0, 0);
#pragma unroll
      for (int reg = 0; reg < 4; ++reg) {
        a2[kk][reg] = (short)f2bf(fmaxf(r0[reg], 0.f));
        a2[kk][4 + reg] = (short)f2bf(fmaxf(r1[reg], 0.f));
      }
    }

    // ---- per-j: G2 (a2 @ w2T global) + G4 (pa @ langT_s) + combine
#pragma unroll
    for (int j = 0; j < 4; ++j) {
      int nt = h * 4 + j;
      f32x4 ro = {b2v[j], b2v[j], b2v[j], b2v[j]};
#pragma unroll
      for (int kk = 0; kk < 4; ++kk) {
        short8 bw =
            *(const short8*)&w2T_bf[(size_t)(nt * 16 + ln) * 128 + kk * 32 + g * 8];
        ro = __builtin_amdgcn_mfma_f32_16x16x32_bf16(a2[kk], bw, ro, 0, 0, 0);
      }
      f32x4 iv = {0.f, 0.f, 0.f, 0.f};
      short8 bl = *(const short8*)&langT_s[(nt * 16 + ln) * 40 + g * 8];
      iv = __builtin_amdgcn_mfma_f32_16x16x32_bf16(pa, bl, iv, 0, 0, 0);
#pragma unroll
      for (int reg = 0; reg < 4; ++reg) {
        float fv = fbase[(size_t)nbrC[reg] * D_ + nt * 16 + ln];
        o[j][reg] += fv * iv[reg] * ro[reg];
      }
    }
  }

  // ---- cross-wave reduction (q2 partner pairs) ----
  __syncthreads();  // all tile work done; arena free for reuse
  float* R = (float*)arena;  // 8 x [64 rows][stride 20] f32 (padded banks)
  {
    float* Rw = R + w * 1280;
#pragma unroll
    for (int j = 0; j < 4; ++j)
      *(f32x4*)&Rw[(j * 16 + ln) * 20 + g * 4] = o[j];
  }
  __syncthreads();
  {
    int wp = og * 4 + h * 2;  // partner pair base (q2 = 0,1)
    float vs[2][4];
#pragma unroll
    for (int t = 0; t < 2; ++t) {
      int j = q2 * 2 + t;
      int col = (h * 4 + j) * 16 + ln;
      f32x4 sum = *(f32x4*)&R[wp * 1280 + (j * 16 + ln) * 20 + g * 4];
      sum += *(f32x4*)&R[(wp + 1) * 1280 + (j * 16 + ln) * 20 + g * 4];
#pragma unroll
      for (int reg = 0; reg < 4; ++reg) {
        int obj = og * 16 + g * 4 + reg;
        float v = sum[reg] + f_out[(size_t)(sn0 + obj) * D_ + col];
        outp[(size_t)(sn0 + obj) * D_ + col] = v;
        vs[t][reg] = v;
      }
    }
#pragma unroll
    for (int reg = 0; reg < 4; ++reg) {
      float sv = vs[0][reg] + vs[1][reg];
      sv += __shfl_xor(sv, 1);
      sv += __shfl_xor(sv, 2);
      sv += __shfl_xor(sv, 4);
      sv += __shfl_xor(sv, 8);
      if (ln == 0) atomicAdd(&score_s[og * 16 + g * 4 + reg], sv);
    }
  }
  __syncthreads();
  if (tid < CH_) score[sn0 + tid] = score_s[tid];
}

extern "C" void kernel_launch(void* const* d_in, const int* in_sizes, int n_in,
                              void* d_out, int out_size, void* d_ws,
                              size_t ws_size, hipStream_t stream) {
  const float* feat = (const float*)d_in[0];
  const float* coord = (const float*)d_in[1];
  const float* lang_feat = (const float*)d_in[2];
  const int* lang_len = (const int*)d_in[3];
  const float* rel_w1 = (const float*)d_in[4];
  const float* rel_b1 = (const float*)d_in[5];
  const float* rel_w2 = (const float*)d_in[6];
  const float* rel_b2 = (const float*)d_in[7];
  const float* lang_w1 = (const float*)d_in[8];
  const float* lang_b1 = (const float*)d_in[9];
  const float* lang_w2 = (const float*)d_in[10];
  const float* lang_b2 = (const float*)d_in[11];
  const float* feat_w1 = (const float*)d_in[12];
  const float* feat_b1 = (const float*)d_in[13];
  const float* feat_w2 = (const float*)d_in[14];
  const float* feat_b2 = (const float*)d_in[15];

  char* ws = (char*)d_ws;
  unsigned short* lang_bf = (unsigned short*)(ws);                  // 512 KB
  unsigned short* langT_bf = (unsigned short*)(ws + 524288);        // 512 KB
  float* f_out = (float*)(ws + 1048576);                            // 8 MB
  unsigned short* f_bf = (unsigned short*)(ws + 9437184);           // 4 MB
  unsigned short* w2T_bf = (unsigned short*)(ws + 14745600);        // 32 KB
  unsigned short* w1T_bf = (unsigned short*)(ws + 14778368);        // 4 KB
  unsigned short* fw1T_bf = (unsigned short*)(ws + 14782464);       // 32 KB
  unsigned short* fw2T_bf = (unsigned short*)(ws + 14815232);       // 32 KB
  unsigned short* lw1T_bf = (unsigned short*)(ws + 14848000);       // 64 KB
  unsigned short* lw2T_bf = (unsigned short*)(ws + 14913536);       // 32 KB

  float* out = (float*)d_out;
  float* score = out + (size_t)S_ * N_ * D_;

  tar_prep_kernel<<<dim3(128), dim3(256), 0, stream>>>(
      rel_w1, rel_b1, rel_w2, feat_w1, feat_w2, lang_w1, lang_w2, w1T_bf,
      w2T_bf, fw1T_bf, fw2T_bf, lw1T_bf, lw2T_bf);
  tar_prologue<<<dim3(LANG_NB + FM_NB), dim3(256), 0, stream>>>(
      lang_feat, lw1T_bf, lang_b1, lw2T_bf, lang_b2, lang_bf, langT_bf, feat,
      fw1T_bf, feat_b1, fw2T_bf, feat_b2, f_out, f_bf);
  tar_main_mfma<<<dim3(S_ * (N_ / CH_)), dim3(512), 0, stream>>>(
      f_out, f_bf, lang_bf, langT_bf, coord, w1T_bf, w2T_bf, rel_b2, lang_len,
      out, score);
}

// Round 16
// 118.276 us; speedup vs baseline: 1.5943x; 1.2473x over previous
//
#include <hip/hip_runtime.h>
#include <math.h>

#define S_ 64
#define N_ 256
#define L_ 32
#define D_ 128
#define LID_ 256
#define K1_ 17
#define CH_ 32    // objects per main block
#define NW_ 8     // waves per main block

typedef __attribute__((ext_vector_type(8))) short short8;
typedef __attribute__((ext_vector_type(4))) float f32x4;

__device__ __forceinline__ unsigned short f2bf(float f) {
  unsigned int u = __float_as_uint(f);
  u += 0x7fffu + ((u >> 16) & 1u);
  return (unsigned short)(u >> 16);
}
// NOTE (round-12): no inline-asm cvt_pk -- each asm stmt is a scheduler
// barrier; 20/iter collapsed ILP (main 74->137us). Manual f2bf only.
// NOTE (round-14): o[8] dedup spills at the 128-VGPR cap (WRITE 8->102MB).
// NOTE (round-15): KNN fused into main = serial low-occupancy prefix,
// main +41us. KNN stays in the high-occupancy prologue.

// K-slot permutations (MFMA K-axis is order-agnostic as long as A and B agree):
// lang tokens: slot(t) = 8*((t&15)>>2) + 4*(t>>4) + (t&3)
// rel hidden : slot(h) = 32*(h>>5) + 8*((h&15)>>2) + 4*((h>>4)&1) + (h&3)

// ---------------------------------------------------------------- weight prep
__global__ __launch_bounds__(256) void tar_prep_kernel(
    const float* __restrict__ rw1, const float* __restrict__ rb1,
    const float* __restrict__ rw2, const float* __restrict__ fw1,
    const float* __restrict__ fw2, const float* __restrict__ lw1,
    const float* __restrict__ lw2, unsigned short* __restrict__ w1T,
    unsigned short* __restrict__ w2T, unsigned short* __restrict__ fw1T,
    unsigned short* __restrict__ fw2T, unsigned short* __restrict__ lw1T,
    unsigned short* __restrict__ lw2T) {
  int t = blockIdx.x * 256 + threadIdx.x;  // 0..32767
  {
    int k = t >> 7, n = t & 127;  // k 0..255 (lang layer1 K=256)
    lw1T[(size_t)n * 256 + k] = f2bf(lw1[(size_t)k * 128 + n]);
  }
  if (t < 16384) {
    int k = t >> 7, n = t & 127;
    int slot =
        32 * (k >> 5) + 8 * ((k & 15) >> 2) + 4 * ((k >> 4) & 1) + (k & 3);
    w2T[(size_t)n * 128 + slot] = f2bf(rw2[(size_t)k * 128 + n]);
    fw1T[(size_t)n * 128 + k] = f2bf(fw1[(size_t)k * 128 + n]);
    fw2T[(size_t)n * 128 + k] = f2bf(fw2[(size_t)k * 128 + n]);
    lw2T[(size_t)n * 128 + k] = f2bf(lw2[(size_t)k * 128 + n]);
  }
  if (t < 2048) {
    int n2 = t >> 4, k2 = t & 15;
    unsigned short v = 0;
    if (k2 < 10) v = f2bf(rw1[(size_t)k2 * 128 + n2]);
    else if (k2 == 10) v = f2bf(rb1[n2]);  // bias slot (rel10 slot10 == 1.0)
    w1T[(size_t)n2 * 16 + k2] = v;
  }
}

// ---------------------------------------------------------------- fused prologue
// roles: [0,1024) knn | [1024,1056) lang MLP (MFMA) | [1056,1312) feat MLP
#define KNN_NB 1024
#define LANG_NB 32
#define FM_NB 256
__global__ __launch_bounds__(256, 4) void tar_prologue(
    const float* __restrict__ coord, int* __restrict__ idx_out,
    const float* __restrict__ lx, const unsigned short* __restrict__ lw1T,
    const float* __restrict__ lb1, const unsigned short* __restrict__ lw2T,
    const float* __restrict__ lb2, unsigned short* __restrict__ lang_bf,
    unsigned short* __restrict__ langT_bf, const float* __restrict__ fx,
    const unsigned short* __restrict__ fw1T, const float* __restrict__ fb1,
    const unsigned short* __restrict__ fw2T, const float* __restrict__ fb2,
    float* __restrict__ f_out, unsigned short* __restrict__ f_bf) {
  __shared__ __align__(16) char uarena[51200];
  int bid = blockIdx.x;
  int tid = threadIdx.x;

  if (bid < KNN_NB) {
    // ---- KNN: block = 16 objects of ONE sentence (16 blocks/sentence).
    //      Round-16: sentence coords staged in LDS (3KB, coalesced) --
    //      the 48 scalar coord reads/lane become LDS broadcasts.
    float* cs_lds = (float*)uarena;  // [768]
    int s = bid >> 4;
    const float* cs = coord + (size_t)s * N_ * 3;
    for (int i = tid; i < 768; i += 256) cs_lds[i] = cs[i];
    __syncthreads();
    int wv = tid >> 6, l = tid & 63, grp = l >> 4, ln16 = l & 15;
    int obj = bid * 16 + wv * 4 + grp;  // 0..16383
    int n = obj & 255;
    float cx = cs_lds[n * 3 + 0], cy = cs_lds[n * 3 + 1],
          cz = cs_lds[n * 3 + 2];
    unsigned kd[16];
#pragma unroll
    for (int q = 0; q < 16; ++q) {
      int j = ln16 + q * 16;
      float dx = cs_lds[j * 3 + 0] - cx;
      float dy = cs_lds[j * 3 + 1] - cy;
      float dz = cs_lds[j * 3 + 2] - cz;
      kd[q] = __float_as_uint(dx * dx + dy * dy + dz * dz);
    }
    for (int k = 0; k < K1_; ++k) {
      unsigned m = kd[0];
#pragma unroll
      for (int q = 1; q < 16; ++q) m = min(m, kd[q]);
      int bq = 0;
#pragma unroll
      for (int q = 15; q >= 0; --q)
        if (kd[q] == m) bq = q;  // lowest q on tie -> lowest j
      int bj = ln16 + bq * 16;
      unsigned bm = m;
#pragma unroll
      for (int off = 1; off <= 8; off <<= 1) {
        unsigned om = __shfl_xor(bm, off);
        int oj = __shfl_xor(bj, off);
        if (om < bm || (om == bm && oj < bj)) { bm = om; bj = oj; }
      }
#pragma unroll
      for (int q = 0; q < 16; ++q)
        if (ln16 + q * 16 == bj) kd[q] = 0xFFFFFFFFu;
      if (ln16 == 0) idx_out[(size_t)obj * K1_ + k] = bj;
    }
  } else if (bid < KNN_NB + LANG_NB) {
    // ---- lang MLP via MFMA: 64 rows/block, K=256 layer1
    unsigned short* x_s = (unsigned short*)uarena;            // [64][264]
    unsigned short* h_s = (unsigned short*)(uarena + 33792);  // 4x[16][136]
    int base = (bid - KNN_NB) * 64;
    int w = tid >> 6, l = tid & 63, g = l >> 4, ln = l & 15;
    for (int i = tid; i < 64 * 64; i += 256) {
      int row = i >> 6, c4 = (i & 63) * 4;
      float4 v = *(const float4*)&lx[(size_t)(base + row) * LID_ + c4];
      unsigned short* dst = &x_s[row * 264 + c4];
      dst[0] = f2bf(v.x); dst[1] = f2bf(v.y);
      dst[2] = f2bf(v.z); dst[3] = f2bf(v.w);
    }
    __syncthreads();
    float b1v[8], b2v[8];
#pragma unroll
    for (int nt = 0; nt < 8; ++nt) {
      b1v[nt] = lb1[nt * 16 + ln];
      b2v[nt] = lb2[nt * 16 + ln];
    }
    short8 a1[8];
#pragma unroll
    for (int kk = 0; kk < 8; ++kk)
      a1[kk] = *(const short8*)&x_s[(w * 16 + ln) * 264 + kk * 32 + g * 8];
    unsigned short* hw = &h_s[w * 16 * 136];
#pragma unroll
    for (int nt = 0; nt < 8; ++nt) {
      f32x4 acc = {b1v[nt], b1v[nt], b1v[nt], b1v[nt]};
#pragma unroll
      for (int kk = 0; kk < 8; ++kk) {
        short8 bw =
            *(const short8*)&lw1T[(size_t)(nt * 16 + ln) * 256 + kk * 32 + g * 8];
        acc = __builtin_amdgcn_mfma_f32_16x16x32_bf16(a1[kk], bw, acc, 0, 0, 0);
      }
#pragma unroll
      for (int reg = 0; reg < 4; ++reg)
        hw[(g * 4 + reg) * 136 + nt * 16 + ln] = f2bf(fmaxf(acc[reg], 0.f));
    }
    short8 a2[4];
#pragma unroll
    for (int kk = 0; kk < 4; ++kk)
      a2[kk] = *(const short8*)&hw[ln * 136 + kk * 32 + g * 8];
#pragma unroll
    for (int nt = 0; nt < 8; ++nt) {
      f32x4 acc = {b2v[nt], b2v[nt], b2v[nt], b2v[nt]};
#pragma unroll
      for (int kk = 0; kk < 4; ++kk) {
        short8 bw =
            *(const short8*)&lw2T[(size_t)(nt * 16 + ln) * 128 + kk * 32 + g * 8];
        acc = __builtin_amdgcn_mfma_f32_16x16x32_bf16(a2[kk], bw, acc, 0, 0, 0);
      }
#pragma unroll
      for (int reg = 0; reg < 4; ++reg) {
        int row = base + w * 16 + g * 4 + reg;
        int col = nt * 16 + ln;
        unsigned short hb = f2bf(acc[reg]);
        lang_bf[(size_t)row * D_ + col] = hb;
        int s = row >> 5, t = row & 31;
        int slot = 8 * ((t & 15) >> 2) + 4 * (t >> 4) + (t & 3);
        langT_bf[((size_t)s * D_ + col) * L_ + slot] = hb;
      }
    }
  } else {
    // ---- feat MLP (MFMA), 64 rows/block
    unsigned short* x_s = (unsigned short*)uarena;            // [64][136]
    unsigned short* h_s = (unsigned short*)(uarena + 17408);  // 4x[16][136]
    int base = (bid - KNN_NB - LANG_NB) * 64;
    int w = tid >> 6, l = tid & 63, g = l >> 4, ln = l & 15;
    for (int i = tid; i < 64 * 32; i += 256) {
      int row = i >> 5, c4 = (i & 31) * 4;
      float4 v = *(const float4*)&fx[(size_t)(base + row) * D_ + c4];
      unsigned short* dst = &x_s[row * 136 + c4];
      dst[0] = f2bf(v.x); dst[1] = f2bf(v.y);
      dst[2] = f2bf(v.z); dst[3] = f2bf(v.w);
    }
    __syncthreads();
    float b1v[8], b2v[8];
#pragma unroll
    for (int nt = 0; nt < 8; ++nt) {
      b1v[nt] = fb1[nt * 16 + ln];
      b2v[nt] = fb2[nt * 16 + ln];
    }
    short8 a1[4];
#pragma unroll
    for (int kk = 0; kk < 4; ++kk)
      a1[kk] = *(const short8*)&x_s[(w * 16 + ln) * 136 + kk * 32 + g * 8];
    unsigned short* hw = &h_s[w * 16 * 136];
#pragma unroll
    for (int nt = 0; nt < 8; ++nt) {
      f32x4 acc = {b1v[nt], b1v[nt], b1v[nt], b1v[nt]};
#pragma unroll
      for (int kk = 0; kk < 4; ++kk) {
        short8 bw =
            *(const short8*)&fw1T[(size_t)(nt * 16 + ln) * 128 + kk * 32 + g * 8];
        acc = __builtin_amdgcn_mfma_f32_16x16x32_bf16(a1[kk], bw, acc, 0, 0, 0);
      }
#pragma unroll
      for (int reg = 0; reg < 4; ++reg)
        hw[(g * 4 + reg) * 136 + nt * 16 + ln] = f2bf(fmaxf(acc[reg], 0.f));
    }
    short8 a2[4];
#pragma unroll
    for (int kk = 0; kk < 4; ++kk)
      a2[kk] = *(const short8*)&hw[ln * 136 + kk * 32 + g * 8];
#pragma unroll
    for (int nt = 0; nt < 8; ++nt) {
      f32x4 acc = {b2v[nt], b2v[nt], b2v[nt], b2v[nt]};
#pragma unroll
      for (int kk = 0; kk < 4; ++kk) {
        short8 bw =
            *(const short8*)&fw2T[(size_t)(nt * 16 + ln) * 128 + kk * 32 + g * 8];
        acc = __builtin_amdgcn_mfma_f32_16x16x32_bf16(a2[kk], bw, acc, 0, 0, 0);
      }
#pragma unroll
      for (int reg = 0; reg < 4; ++reg) {
        int row = base + w * 16 + g * 4 + reg;
        int col = nt * 16 + ln;
        f_out[(size_t)row * D_ + col] = acc[reg];
        f_bf[(size_t)row * D_ + col] = f2bf(acc[reg]);
      }
    }
  }
}

// ---------------------------------------------------------------- main MFMA
// block = (sentence, 32 objects), 8 waves = (og, h, q2). Swapped-operand
// MFMAs keep P/relh in registers (obj = lane&15 columns); K-slot permutation
// baked into langT/w2T producers. w2T from GLOBAL (round 11), no inline asm
// (round 12). (512,2): arg2 acts as blocks/CU -> 128-VGPR cap, no spills.
__global__ __launch_bounds__(512, 2) void tar_main_mfma(
    const float* __restrict__ f_out, const unsigned short* __restrict__ f_bf,
    const unsigned short* __restrict__ lang_bf,
    const unsigned short* __restrict__ langT_bf, const int* __restrict__ idxg,
    const float* __restrict__ coord, const unsigned short* __restrict__ w1T_bf,
    const unsigned short* __restrict__ w2T_bf, const float* __restrict__ rel_b2,
    const int* __restrict__ lang_len, float* __restrict__ outp,
    float* __restrict__ score) {
  // staging: lang_s [32][136]u16 @0 (8704) | langT_s [128][40]u16 @8704
  //          (10240) | w1T_s [128][24]u16 @18944 (6144) | idx_s @25088 (2176)
  //          = 27264 B; epilogue aliases arena as R = 8x[64][20] f32 (40960)
  __shared__ __align__(16) char arena[40960];
  __shared__ float score_s[CH_];

  unsigned short* lang_s = (unsigned short*)(arena);
  unsigned short* langT_s = (unsigned short*)(arena + 8704);
  unsigned short* w1T_s = (unsigned short*)(arena + 18944);
  int* idx_s = (int*)(arena + 25088);

  int b = blockIdx.x;
  int s = b >> 3;
  int chunk = b & 7;
  int sn0 = s * N_ + chunk * CH_;
  int tid = threadIdx.x;
  int w = tid >> 6;
  int l = tid & 63;
  int g = l >> 4;
  int ln = l & 15;
  int og = w >> 2;        // object group (0/1)
  int h = (w >> 1) & 1;   // nt half: tiles h*4 .. h*4+3
  int q2 = w & 1;         // k parity
  int len = lang_len[s];

  {
    int row = tid >> 4, c0 = (tid & 15) * 8;
    *(short8*)&lang_s[row * 136 + c0] =
        *(const short8*)&lang_bf[((size_t)s * L_ + row) * D_ + c0];
  }
  {
    int row = tid >> 2, c0 = (tid & 3) * 8;
    *(short8*)&langT_s[row * 40 + c0] =
        *(const short8*)&langT_bf[((size_t)s * D_ + row) * L_ + c0];
  }
  if (tid < 256) {
    int row = tid >> 1, c0 = (tid & 1) * 8;
    *(short8*)&w1T_s[row * 24 + c0] =
        *(const short8*)&w1T_bf[(size_t)row * 16 + c0];
  }
  for (int i = tid; i < CH_ * K1_; i += 512)
    idx_s[i] = idxg[(size_t)sn0 * K1_ + i];
  if (tid < CH_) score_s[tid] = 0.f;
  __syncthreads();

  float b2v[4];
#pragma unroll
  for (int j = 0; j < 4; ++j) b2v[j] = rel_b2[(h * 4 + j) * 16 + ln];

  f32x4 o[4];
#pragma unroll
  for (int j = 0; j < 4; ++j) o[j] = (f32x4){0.f, 0.f, 0.f, 0.f};

  int objA = og * 16 + ln;  // this lane's obj (B-row / column owner)
  const float* fbase = &f_out[(size_t)s * N_ * D_];
  const float* cA = coord + (size_t)(sn0 + objA) * 3;
  float cx = cA[0], cy = cA[1], cz = cA[2];

  for (int k = q2; k < K1_; k += 2) {
    int nbrA = idx_s[objA * K1_ + k];
    int nbrC[4];
#pragma unroll
    for (int reg = 0; reg < 4; ++reg)
      nbrC[reg] = idx_s[(og * 16 + g * 4 + reg) * K1_ + k];

    // ---- rel10 inline from coords (issued early; hides under G3)
    const float* cN = coord + (size_t)(s * N_ + nbrA) * 3;
    float nx = cN[0], ny = cN[1], nz = cN[2];
    float rx = nx - cx, ry = ny - cy, rz = nz - cz;
    float dist = sqrtf(rx * rx + ry * ry + rz * rz);
    short8 a1v = {0, 0, 0, 0, 0, 0, 0, 0};
    if (g == 0) {
      a1v[0] = (short)f2bf(nx); a1v[1] = (short)f2bf(ny);
      a1v[2] = (short)f2bf(nz); a1v[3] = (short)f2bf(cx);
      a1v[4] = (short)f2bf(cy); a1v[5] = (short)f2bf(cz);
      a1v[6] = (short)f2bf(rx); a1v[7] = (short)f2bf(ry);
    } else if (g == 1) {
      a1v[0] = (short)f2bf(rz);
      a1v[1] = (short)f2bf(dist);
      a1v[2] = (short)0x3F80;  // 1.0 -> bias slot 10
    }

    const unsigned short* fArow = &f_bf[((size_t)s * N_ + nbrA) * D_];

    // ---- G3 swapped: at = lang @ f_nb^T -> C[token][obj], obj = ln
    f32x4 at0 = {0.f, 0.f, 0.f, 0.f}, at1 = {0.f, 0.f, 0.f, 0.f};
#pragma unroll
    for (int kk = 0; kk < 4; ++kk) {
      short8 fA = *(const short8*)&fArow[kk * 32 + g * 8];
      short8 bb0 = *(const short8*)&lang_s[ln * 136 + kk * 32 + g * 8];
      short8 bb1 = *(const short8*)&lang_s[(16 + ln) * 136 + kk * 32 + g * 8];
      at0 = __builtin_amdgcn_mfma_f32_16x16x32_bf16(bb0, fA, at0, 0, 0, 0);
      at1 = __builtin_amdgcn_mfma_f32_16x16x32_bf16(bb1, fA, at1, 0, 0, 0);
    }

    // ---- softmax for obj ln: tokens at0->4g+reg, at1->16+4g+reg.
    //      local over 8 + shfl_xor(16,32). ref-exact algebra.
    float mx = fmaxf(fmaxf(fmaxf(at0[0], at0[1]), fmaxf(at0[2], at0[3])),
                     fmaxf(fmaxf(at1[0], at1[1]), fmaxf(at1[2], at1[3])));
    mx = fmaxf(mx, __shfl_xor(mx, 16));
    mx = fmaxf(mx, __shfl_xor(mx, 32));
    float e0[4], e1[4], p0[4], p1[4];
    float ss = 0.f, ms = 0.f;
#pragma unroll
    for (int reg = 0; reg < 4; ++reg) {
      e0[reg] = expf(at0[reg] - mx);
      e1[reg] = expf(at1[reg] - mx);
      ss += e0[reg] + e1[reg];
      p0[reg] = (4 * g + reg < len) ? e0[reg] : 0.f;
      p1[reg] = (16 + 4 * g + reg < len) ? e1[reg] : 0.f;
      ms += p0[reg] + p1[reg];
    }
    ss += __shfl_xor(ss, 16);
    ss += __shfl_xor(ss, 32);
    ms += __shfl_xor(ms, 16);
    ms += __shfl_xor(ms, 32);
    float inv = 1.0f / (ms + 1e-7f * ss);  // == q/ssum / (ms/ssum + 1e-7)
    short8 pa;
#pragma unroll
    for (int reg = 0; reg < 4; ++reg) {
      pa[reg] = (short)f2bf(p0[reg] * inv);
      pa[4 + reg] = (short)f2bf(p1[reg] * inv);
    }

    // ---- G1 swapped: relh = w1T-chunks @ rel10 -> C[h][obj], obj = ln.
    //      relu + pack to a2 (K-slot perm matches w2T prep).
    short8 a2[4];
#pragma unroll
    for (int kk = 0; kk < 4; ++kk) {
      short8 bw0 = {0, 0, 0, 0, 0, 0, 0, 0};
      short8 bw1 = {0, 0, 0, 0, 0, 0, 0, 0};
      if (g < 2) {
        bw0 = *(const short8*)&w1T_s[((2 * kk) * 16 + ln) * 24 + g * 8];
        bw1 = *(const short8*)&w1T_s[((2 * kk + 1) * 16 + ln) * 24 + g * 8];
      }
      f32x4 z = {0.f, 0.f, 0.f, 0.f};
      f32x4 r0 = __builtin_amdgcn_mfma_f32_16x16x32_bf16(bw0, a1v, z, 0, 0, 0);
      f32x4 r1 = __builtin_amdgcn_mfma_f32_16x16x32_bf16(bw1, a1v, z, 0, 0, 0);
#pragma unroll
      for (int reg = 0; reg < 4; ++reg) {
        a2[kk][reg] = (short)f2bf(fmaxf(r0[reg], 0.f));
        a2[kk][4 + reg] = (short)f2bf(fmaxf(r1[reg], 0.f));
      }
    }

    // ---- per-j: G2 (a2 @ w2T global) + G4 (pa @ langT_s) + combine
#pragma unroll
    for (int j = 0; j < 4; ++j) {
      int nt = h * 4 + j;
      f32x4 ro = {b2v[j], b2v[j], b2v[j], b2v[j]};
#pragma unroll
      for (int kk = 0; kk < 4; ++kk) {
        short8 bw =
            *(const short8*)&w2T_bf[(size_t)(nt * 16 + ln) * 128 + kk * 32 + g * 8];
        ro = __builtin_amdgcn_mfma_f32_16x16x32_bf16(a2[kk], bw, ro, 0, 0, 0);
      }
      f32x4 iv = {0.f, 0.f, 0.f, 0.f};
      short8 bl = *(const short8*)&langT_s[(nt * 16 + ln) * 40 + g * 8];
      iv = __builtin_amdgcn_mfma_f32_16x16x32_bf16(pa, bl, iv, 0, 0, 0);
#pragma unroll
      for (int reg = 0; reg < 4; ++reg) {
        float fv = fbase[(size_t)nbrC[reg] * D_ + nt * 16 + ln];
        o[j][reg] += fv * iv[reg] * ro[reg];
      }
    }
  }

  // ---- cross-wave reduction (q2 partner pairs) ----
  __syncthreads();  // all tile work done; arena free for reuse
  float* R = (float*)arena;  // 8 x [64 rows][stride 20] f32 (padded banks)
  {
    float* Rw = R + w * 1280;
#pragma unroll
    for (int j = 0; j < 4; ++j)
      *(f32x4*)&Rw[(j * 16 + ln) * 20 + g * 4] = o[j];
  }
  __syncthreads();
  {
    int wp = og * 4 + h * 2;  // partner pair base (q2 = 0,1)
    float vs[2][4];
#pragma unroll
    for (int t = 0; t < 2; ++t) {
      int j = q2 * 2 + t;
      int col = (h * 4 + j) * 16 + ln;
      f32x4 sum = *(f32x4*)&R[wp * 1280 + (j * 16 + ln) * 20 + g * 4];
      sum += *(f32x4*)&R[(wp + 1) * 1280 + (j * 16 + ln) * 20 + g * 4];
#pragma unroll
      for (int reg = 0; reg < 4; ++reg) {
        int obj = og * 16 + g * 4 + reg;
        float v = sum[reg] + f_out[(size_t)(sn0 + obj) * D_ + col];
        outp[(size_t)(sn0 + obj) * D_ + col] = v;
        vs[t][reg] = v;
      }
    }
#pragma unroll
    for (int reg = 0; reg < 4; ++reg) {
      float sv = vs[0][reg] + vs[1][reg];
      sv += __shfl_xor(sv, 1);
      sv += __shfl_xor(sv, 2);
      sv += __shfl_xor(sv, 4);
      sv += __shfl_xor(sv, 8);
      if (ln == 0) atomicAdd(&score_s[og * 16 + g * 4 + reg], sv);
    }
  }
  __syncthreads();
  if (tid < CH_) score[sn0 + tid] = score_s[tid];
}

extern "C" void kernel_launch(void* const* d_in, const int* in_sizes, int n_in,
                              void* d_out, int out_size, void* d_ws,
                              size_t ws_size, hipStream_t stream) {
  const float* feat = (const float*)d_in[0];
  const float* coord = (const float*)d_in[1];
  const float* lang_feat = (const float*)d_in[2];
  const int* lang_len = (const int*)d_in[3];
  const float* rel_w1 = (const float*)d_in[4];
  const float* rel_b1 = (const float*)d_in[5];
  const float* rel_w2 = (const float*)d_in[6];
  const float* rel_b2 = (const float*)d_in[7];
  const float* lang_w1 = (const float*)d_in[8];
  const float* lang_b1 = (const float*)d_in[9];
  const float* lang_w2 = (const float*)d_in[10];
  const float* lang_b2 = (const float*)d_in[11];
  const float* feat_w1 = (const float*)d_in[12];
  const float* feat_b1 = (const float*)d_in[13];
  const float* feat_w2 = (const float*)d_in[14];
  const float* feat_b2 = (const float*)d_in[15];

  char* ws = (char*)d_ws;
  unsigned short* lang_bf = (unsigned short*)(ws);                  // 512 KB
  unsigned short* langT_bf = (unsigned short*)(ws + 524288);        // 512 KB
  float* f_out = (float*)(ws + 1048576);                            // 8 MB
  unsigned short* f_bf = (unsigned short*)(ws + 9437184);           // 4 MB
  int* idx = (int*)(ws + 13631488);                                 // ~1.1 MB
  unsigned short* w2T_bf = (unsigned short*)(ws + 14745600);        // 32 KB
  unsigned short* w1T_bf = (unsigned short*)(ws + 14778368);        // 4 KB
  unsigned short* fw1T_bf = (unsigned short*)(ws + 14782464);       // 32 KB
  unsigned short* fw2T_bf = (unsigned short*)(ws + 14815232);       // 32 KB
  unsigned short* lw1T_bf = (unsigned short*)(ws + 14848000);       // 64 KB
  unsigned short* lw2T_bf = (unsigned short*)(ws + 14913536);       // 32 KB

  float* out = (float*)d_out;
  float* score = out + (size_t)S_ * N_ * D_;

  tar_prep_kernel<<<dim3(128), dim3(256), 0, stream>>>(
      rel_w1, rel_b1, rel_w2, feat_w1, feat_w2, lang_w1, lang_w2, w1T_bf,
      w2T_bf, fw1T_bf, fw2T_bf, lw1T_bf, lw2T_bf);
  tar_prologue<<<dim3(KNN_NB + LANG_NB + FM_NB), dim3(256), 0, stream>>>(
      coord, idx, lang_feat, lw1T_bf, lang_b1, lw2T_bf, lang_b2, lang_bf,
      langT_bf, feat, fw1T_bf, feat_b1, fw2T_bf, feat_b2, f_out, f_bf);
  tar_main_mfma<<<dim3(S_ * (N_ / CH_)), dim3(512), 0, stream>>>(
      f_out, f_bf, lang_bf, langT_bf, idx, coord, w1T_bf, w2T_bf, rel_b2,
      lang_len, out, score);
}

// Round 17
// 110.087 us; speedup vs baseline: 1.7129x; 1.0744x over previous
//
#include <hip/hip_runtime.h>
#include <math.h>

#define S_ 64
#define N_ 256
#define L_ 32
#define D_ 128
#define LID_ 256
#define K1_ 17
#define CH_ 32    // objects per main block
#define NW_ 8     // waves per main block

typedef __attribute__((ext_vector_type(8))) short short8;
typedef __attribute__((ext_vector_type(4))) float f32x4;

__device__ __forceinline__ unsigned short f2bf(float f) {
  unsigned int u = __float_as_uint(f);
  u += 0x7fffu + ((u >> 16) & 1u);
  return (unsigned short)(u >> 16);
}
// NOTE (round-12): no inline-asm cvt_pk -- scheduler barrier, ILP collapse.
// NOTE (round-14): o[8] dedup spills at the 128-VGPR cap.
// NOTE (round-15): KNN fused into main = serial low-occupancy prefix (+41us).

// K-slot permutations (MFMA K-axis is order-agnostic as long as A and B agree):
// lang tokens: slot(t) = 8*((t&15)>>2) + 4*(t>>4) + (t&3)
// rel hidden : slot(h) = 32*(h>>5) + 8*((h&15)>>2) + 4*((h>>4)&1) + (h&3)

// ---------------------------------------------------------------- weight prep
__global__ __launch_bounds__(256) void tar_prep_kernel(
    const float* __restrict__ rw1, const float* __restrict__ rb1,
    const float* __restrict__ rw2, const float* __restrict__ fw1,
    const float* __restrict__ fw2, const float* __restrict__ lw1,
    const float* __restrict__ lw2, unsigned short* __restrict__ w1T,
    unsigned short* __restrict__ w2T, unsigned short* __restrict__ fw1T,
    unsigned short* __restrict__ fw2T, unsigned short* __restrict__ lw1T,
    unsigned short* __restrict__ lw2T) {
  int t = blockIdx.x * 256 + threadIdx.x;  // 0..32767
  {
    int k = t >> 7, n = t & 127;  // k 0..255 (lang layer1 K=256)
    lw1T[(size_t)n * 256 + k] = f2bf(lw1[(size_t)k * 128 + n]);
  }
  if (t < 16384) {
    int k = t >> 7, n = t & 127;
    int slot =
        32 * (k >> 5) + 8 * ((k & 15) >> 2) + 4 * ((k >> 4) & 1) + (k & 3);
    w2T[(size_t)n * 128 + slot] = f2bf(rw2[(size_t)k * 128 + n]);
    fw1T[(size_t)n * 128 + k] = f2bf(fw1[(size_t)k * 128 + n]);
    fw2T[(size_t)n * 128 + k] = f2bf(fw2[(size_t)k * 128 + n]);
    lw2T[(size_t)n * 128 + k] = f2bf(lw2[(size_t)k * 128 + n]);
  }
  if (t < 2048) {
    int n2 = t >> 4, k2 = t & 15;
    unsigned short v = 0;
    if (k2 < 10) v = f2bf(rw1[(size_t)k2 * 128 + n2]);
    else if (k2 == 10) v = f2bf(rb1[n2]);  // bias slot (rel10 slot10 == 1.0)
    w1T[(size_t)n2 * 16 + k2] = v;
  }
}

// ---------------------------------------------------------------- fused prologue
// roles: [0,1024) knn | [1024,1056) lang MLP (MFMA) | [1056,1312) feat MLP
// Round-17: uarena 51.2->34.8KB (lang h_s overlaid onto x_s) -> 4 blocks/CU.
#define KNN_NB 1024
#define LANG_NB 32
#define FM_NB 256
__global__ __launch_bounds__(256, 4) void tar_prologue(
    const float* __restrict__ coord, int* __restrict__ idx_out,
    const float* __restrict__ lx, const unsigned short* __restrict__ lw1T,
    const float* __restrict__ lb1, const unsigned short* __restrict__ lw2T,
    const float* __restrict__ lb2, unsigned short* __restrict__ lang_bf,
    unsigned short* __restrict__ langT_bf, const float* __restrict__ fx,
    const unsigned short* __restrict__ fw1T, const float* __restrict__ fb1,
    const unsigned short* __restrict__ fw2T, const float* __restrict__ fb2,
    float* __restrict__ f_out, unsigned short* __restrict__ f_bf) {
  __shared__ __align__(16) char uarena[34816];
  int bid = blockIdx.x;
  int tid = threadIdx.x;

  if (bid < KNN_NB) {
    // ---- KNN: block = 16 objects of ONE sentence; coords staged in LDS.
    float* cs_lds = (float*)uarena;  // [768]
    int s = bid >> 4;
    const float* cs = coord + (size_t)s * N_ * 3;
    for (int i = tid; i < 768; i += 256) cs_lds[i] = cs[i];
    __syncthreads();
    int wv = tid >> 6, l = tid & 63, grp = l >> 4, ln16 = l & 15;
    int obj = bid * 16 + wv * 4 + grp;  // 0..16383
    int n = obj & 255;
    float cx = cs_lds[n * 3 + 0], cy = cs_lds[n * 3 + 1],
          cz = cs_lds[n * 3 + 2];
    unsigned kd[16];
#pragma unroll
    for (int q = 0; q < 16; ++q) {
      int j = ln16 + q * 16;
      float dx = cs_lds[j * 3 + 0] - cx;
      float dy = cs_lds[j * 3 + 1] - cy;
      float dz = cs_lds[j * 3 + 2] - cz;
      kd[q] = __float_as_uint(dx * dx + dy * dy + dz * dz);
    }
    for (int k = 0; k < K1_; ++k) {
      unsigned m = kd[0];
#pragma unroll
      for (int q = 1; q < 16; ++q) m = min(m, kd[q]);
      int bq = 0;
#pragma unroll
      for (int q = 15; q >= 0; --q)
        if (kd[q] == m) bq = q;  // lowest q on tie -> lowest j
      int bj = ln16 + bq * 16;
      unsigned bm = m;
#pragma unroll
      for (int off = 1; off <= 8; off <<= 1) {
        unsigned om = __shfl_xor(bm, off);
        int oj = __shfl_xor(bj, off);
        if (om < bm || (om == bm && oj < bj)) { bm = om; bj = oj; }
      }
#pragma unroll
      for (int q = 0; q < 16; ++q)
        if (ln16 + q * 16 == bj) kd[q] = 0xFFFFFFFFu;
      if (ln16 == 0) idx_out[(size_t)obj * K1_ + k] = bj;
    }
  } else if (bid < KNN_NB + LANG_NB) {
    // ---- lang MLP via MFMA: 64 rows/block, K=256 layer1.
    //      h overlaid onto x_s after a1 fragments are register-resident.
    unsigned short* x_s = (unsigned short*)uarena;  // [64][264] (33792 B)
    unsigned short* h_s = (unsigned short*)uarena;  // overlay: 4x[16][136]
    int base = (bid - KNN_NB) * 64;
    int w = tid >> 6, l = tid & 63, g = l >> 4, ln = l & 15;
    for (int i = tid; i < 64 * 64; i += 256) {
      int row = i >> 6, c4 = (i & 63) * 4;
      float4 v = *(const float4*)&lx[(size_t)(base + row) * LID_ + c4];
      unsigned short* dst = &x_s[row * 264 + c4];
      dst[0] = f2bf(v.x); dst[1] = f2bf(v.y);
      dst[2] = f2bf(v.z); dst[3] = f2bf(v.w);
    }
    __syncthreads();
    float b1v[8], b2v[8];
#pragma unroll
    for (int nt = 0; nt < 8; ++nt) {
      b1v[nt] = lb1[nt * 16 + ln];
      b2v[nt] = lb2[nt * 16 + ln];
    }
    short8 a1[8];
#pragma unroll
    for (int kk = 0; kk < 8; ++kk)
      a1[kk] = *(const short8*)&x_s[(w * 16 + ln) * 264 + kk * 32 + g * 8];
    __syncthreads();  // all x_s reads done -> safe to overlay h
    unsigned short* hw = &h_s[w * 16 * 136];
#pragma unroll
    for (int nt = 0; nt < 8; ++nt) {
      f32x4 acc = {b1v[nt], b1v[nt], b1v[nt], b1v[nt]};
#pragma unroll
      for (int kk = 0; kk < 8; ++kk) {
        short8 bw =
            *(const short8*)&lw1T[(size_t)(nt * 16 + ln) * 256 + kk * 32 + g * 8];
        acc = __builtin_amdgcn_mfma_f32_16x16x32_bf16(a1[kk], bw, acc, 0, 0, 0);
      }
#pragma unroll
      for (int reg = 0; reg < 4; ++reg)
        hw[(g * 4 + reg) * 136 + nt * 16 + ln] = f2bf(fmaxf(acc[reg], 0.f));
    }
    short8 a2[4];
#pragma unroll
    for (int kk = 0; kk < 4; ++kk)
      a2[kk] = *(const short8*)&hw[ln * 136 + kk * 32 + g * 8];
#pragma unroll
    for (int nt = 0; nt < 8; ++nt) {
      f32x4 acc = {b2v[nt], b2v[nt], b2v[nt], b2v[nt]};
#pragma unroll
      for (int kk = 0; kk < 4; ++kk) {
        short8 bw =
            *(const short8*)&lw2T[(size_t)(nt * 16 + ln) * 128 + kk * 32 + g * 8];
        acc = __builtin_amdgcn_mfma_f32_16x16x32_bf16(a2[kk], bw, acc, 0, 0, 0);
      }
#pragma unroll
      for (int reg = 0; reg < 4; ++reg) {
        int row = base + w * 16 + g * 4 + reg;
        int col = nt * 16 + ln;
        unsigned short hb = f2bf(acc[reg]);
        lang_bf[(size_t)row * D_ + col] = hb;
        int s = row >> 5, t = row & 31;
        int slot = 8 * ((t & 15) >> 2) + 4 * (t >> 4) + (t & 3);
        langT_bf[((size_t)s * D_ + col) * L_ + slot] = hb;
      }
    }
  } else {
    // ---- feat MLP (MFMA), 64 rows/block
    unsigned short* x_s = (unsigned short*)uarena;            // [64][136]
    unsigned short* h_s = (unsigned short*)(uarena + 17408);  // 4x[16][136]
    int base = (bid - KNN_NB - LANG_NB) * 64;
    int w = tid >> 6, l = tid & 63, g = l >> 4, ln = l & 15;
    for (int i = tid; i < 64 * 32; i += 256) {
      int row = i >> 5, c4 = (i & 31) * 4;
      float4 v = *(const float4*)&fx[(size_t)(base + row) * D_ + c4];
      unsigned short* dst = &x_s[row * 136 + c4];
      dst[0] = f2bf(v.x); dst[1] = f2bf(v.y);
      dst[2] = f2bf(v.z); dst[3] = f2bf(v.w);
    }
    __syncthreads();
    float b1v[8], b2v[8];
#pragma unroll
    for (int nt = 0; nt < 8; ++nt) {
      b1v[nt] = fb1[nt * 16 + ln];
      b2v[nt] = fb2[nt * 16 + ln];
    }
    short8 a1[4];
#pragma unroll
    for (int kk = 0; kk < 4; ++kk)
      a1[kk] = *(const short8*)&x_s[(w * 16 + ln) * 136 + kk * 32 + g * 8];
    unsigned short* hw = &h_s[w * 16 * 136];
#pragma unroll
    for (int nt = 0; nt < 8; ++nt) {
      f32x4 acc = {b1v[nt], b1v[nt], b1v[nt], b1v[nt]};
#pragma unroll
      for (int kk = 0; kk < 4; ++kk) {
        short8 bw =
            *(const short8*)&fw1T[(size_t)(nt * 16 + ln) * 128 + kk * 32 + g * 8];
        acc = __builtin_amdgcn_mfma_f32_16x16x32_bf16(a1[kk], bw, acc, 0, 0, 0);
      }
#pragma unroll
      for (int reg = 0; reg < 4; ++reg)
        hw[(g * 4 + reg) * 136 + nt * 16 + ln] = f2bf(fmaxf(acc[reg], 0.f));
    }
    short8 a2[4];
#pragma unroll
    for (int kk = 0; kk < 4; ++kk)
      a2[kk] = *(const short8*)&hw[ln * 136 + kk * 32 + g * 8];
#pragma unroll
    for (int nt = 0; nt < 8; ++nt) {
      f32x4 acc = {b2v[nt], b2v[nt], b2v[nt], b2v[nt]};
#pragma unroll
      for (int kk = 0; kk < 4; ++kk) {
        short8 bw =
            *(const short8*)&fw2T[(size_t)(nt * 16 + ln) * 128 + kk * 32 + g * 8];
        acc = __builtin_amdgcn_mfma_f32_16x16x32_bf16(a2[kk], bw, acc, 0, 0, 0);
      }
#pragma unroll
      for (int reg = 0; reg < 4; ++reg) {
        int row = base + w * 16 + g * 4 + reg;
        int col = nt * 16 + ln;
        f_out[(size_t)row * D_ + col] = acc[reg];
        f_bf[(size_t)row * D_ + col] = f2bf(acc[reg]);
      }
    }
  }
}

// ---------------------------------------------------------------- main MFMA
// block = (sentence, 32 objects), 8 waves = (og, h, q2). Round-17: sentence-
// major XCD swizzle -- s = b & 63, chunk = b >> 6, so all 8 chunk-blocks of a
// sentence are congruent mod 8 -> same XCD -> the sentence's f_out/f_bf
// gather set lives in ONE L2 (was 8x re-fetch: FETCH 56MB vs ~14MB unique).
__global__ __launch_bounds__(512, 2) void tar_main_mfma(
    const float* __restrict__ f_out, const unsigned short* __restrict__ f_bf,
    const unsigned short* __restrict__ lang_bf,
    const unsigned short* __restrict__ langT_bf, const int* __restrict__ idxg,
    const float* __restrict__ coord, const unsigned short* __restrict__ w1T_bf,
    const unsigned short* __restrict__ w2T_bf, const float* __restrict__ rel_b2,
    const int* __restrict__ lang_len, float* __restrict__ outp,
    float* __restrict__ score) {
  // staging: lang_s [32][136]u16 @0 (8704) | langT_s [128][40]u16 @8704
  //          (10240) | w1T_s [128][24]u16 @18944 (6144) | idx_s @25088 (2176)
  //          = 27264 B; epilogue aliases arena as R = 8x[64][20] f32 (40960)
  __shared__ __align__(16) char arena[40960];
  __shared__ float score_s[CH_];

  unsigned short* lang_s = (unsigned short*)(arena);
  unsigned short* langT_s = (unsigned short*)(arena + 8704);
  unsigned short* w1T_s = (unsigned short*)(arena + 18944);
  int* idx_s = (int*)(arena + 25088);

  int b = blockIdx.x;
  int s = b & 63;       // sentence-major decode (XCD swizzle)
  int chunk = b >> 6;   // 0..7
  int sn0 = s * N_ + chunk * CH_;
  int tid = threadIdx.x;
  int w = tid >> 6;
  int l = tid & 63;
  int g = l >> 4;
  int ln = l & 15;
  int og = w >> 2;        // object group (0/1)
  int h = (w >> 1) & 1;   // nt half: tiles h*4 .. h*4+3
  int q2 = w & 1;         // k parity
  int len = lang_len[s];

  {
    int row = tid >> 4, c0 = (tid & 15) * 8;
    *(short8*)&lang_s[row * 136 + c0] =
        *(const short8*)&lang_bf[((size_t)s * L_ + row) * D_ + c0];
  }
  {
    int row = tid >> 2, c0 = (tid & 3) * 8;
    *(short8*)&langT_s[row * 40 + c0] =
        *(const short8*)&langT_bf[((size_t)s * D_ + row) * L_ + c0];
  }
  if (tid < 256) {
    int row = tid >> 1, c0 = (tid & 1) * 8;
    *(short8*)&w1T_s[row * 24 + c0] =
        *(const short8*)&w1T_bf[(size_t)row * 16 + c0];
  }
  for (int i = tid; i < CH_ * K1_; i += 512)
    idx_s[i] = idxg[(size_t)sn0 * K1_ + i];
  if (tid < CH_) score_s[tid] = 0.f;
  __syncthreads();

  float b2v[4];
#pragma unroll
  for (int j = 0; j < 4; ++j) b2v[j] = rel_b2[(h * 4 + j) * 16 + ln];

  f32x4 o[4];
#pragma unroll
  for (int j = 0; j < 4; ++j) o[j] = (f32x4){0.f, 0.f, 0.f, 0.f};

  int objA = og * 16 + ln;  // this lane's obj (B-row / column owner)
  const float* fbase = &f_out[(size_t)s * N_ * D_];
  const float* cA = coord + (size_t)(sn0 + objA) * 3;
  float cx = cA[0], cy = cA[1], cz = cA[2];

  for (int k = q2; k < K1_; k += 2) {
    int nbrA = idx_s[objA * K1_ + k];
    int nbrC[4];
#pragma unroll
    for (int reg = 0; reg < 4; ++reg)
      nbrC[reg] = idx_s[(og * 16 + g * 4 + reg) * K1_ + k];

    // ---- rel10 inline from coords (issued early; hides under G3)
    const float* cN = coord + (size_t)(s * N_ + nbrA) * 3;
    float nx = cN[0], ny = cN[1], nz = cN[2];
    float rx = nx - cx, ry = ny - cy, rz = nz - cz;
    float dist = sqrtf(rx * rx + ry * ry + rz * rz);
    short8 a1v = {0, 0, 0, 0, 0, 0, 0, 0};
    if (g == 0) {
      a1v[0] = (short)f2bf(nx); a1v[1] = (short)f2bf(ny);
      a1v[2] = (short)f2bf(nz); a1v[3] = (short)f2bf(cx);
      a1v[4] = (short)f2bf(cy); a1v[5] = (short)f2bf(cz);
      a1v[6] = (short)f2bf(rx); a1v[7] = (short)f2bf(ry);
    } else if (g == 1) {
      a1v[0] = (short)f2bf(rz);
      a1v[1] = (short)f2bf(dist);
      a1v[2] = (short)0x3F80;  // 1.0 -> bias slot 10
    }

    const unsigned short* fArow = &f_bf[((size_t)s * N_ + nbrA) * D_];

    // ---- G3 swapped: at = lang @ f_nb^T -> C[token][obj], obj = ln
    f32x4 at0 = {0.f, 0.f, 0.f, 0.f}, at1 = {0.f, 0.f, 0.f, 0.f};
#pragma unroll
    for (int kk = 0; kk < 4; ++kk) {
      short8 fA = *(const short8*)&fArow[kk * 32 + g * 8];
      short8 bb0 = *(const short8*)&lang_s[ln * 136 + kk * 32 + g * 8];
      short8 bb1 = *(const short8*)&lang_s[(16 + ln) * 136 + kk * 32 + g * 8];
      at0 = __builtin_amdgcn_mfma_f32_16x16x32_bf16(bb0, fA, at0, 0, 0, 0);
      at1 = __builtin_amdgcn_mfma_f32_16x16x32_bf16(bb1, fA, at1, 0, 0, 0);
    }

    // ---- softmax for obj ln: tokens at0->4g+reg, at1->16+4g+reg.
    //      local over 8 + shfl_xor(16,32). ref-exact algebra.
    float mx = fmaxf(fmaxf(fmaxf(at0[0], at0[1]), fmaxf(at0[2], at0[3])),
                     fmaxf(fmaxf(at1[0], at1[1]), fmaxf(at1[2], at1[3])));
    mx = fmaxf(mx, __shfl_xor(mx, 16));
    mx = fmaxf(mx, __shfl_xor(mx, 32));
    float e0[4], e1[4], p0[4], p1[4];
    float ss = 0.f, ms = 0.f;
#pragma unroll
    for (int reg = 0; reg < 4; ++reg) {
      e0[reg] = expf(at0[reg] - mx);
      e1[reg] = expf(at1[reg] - mx);
      ss += e0[reg] + e1[reg];
      p0[reg] = (4 * g + reg < len) ? e0[reg] : 0.f;
      p1[reg] = (16 + 4 * g + reg < len) ? e1[reg] : 0.f;
      ms += p0[reg] + p1[reg];
    }
    ss += __shfl_xor(ss, 16);
    ss += __shfl_xor(ss, 32);
    ms += __shfl_xor(ms, 16);
    ms += __shfl_xor(ms, 32);
    float inv = 1.0f / (ms + 1e-7f * ss);  // == q/ssum / (ms/ssum + 1e-7)
    short8 pa;
#pragma unroll
    for (int reg = 0; reg < 4; ++reg) {
      pa[reg] = (short)f2bf(p0[reg] * inv);
      pa[4 + reg] = (short)f2bf(p1[reg] * inv);
    }

    // ---- G1 swapped: relh = w1T-chunks @ rel10 -> C[h][obj], obj = ln.
    //      relu + pack to a2 (K-slot perm matches w2T prep).
    short8 a2[4];
#pragma unroll
    for (int kk = 0; kk < 4; ++kk) {
      short8 bw0 = {0, 0, 0, 0, 0, 0, 0, 0};
      short8 bw1 = {0, 0, 0, 0, 0, 0, 0, 0};
      if (g < 2) {
        bw0 = *(const short8*)&w1T_s[((2 * kk) * 16 + ln) * 24 + g * 8];
        bw1 = *(const short8*)&w1T_s[((2 * kk + 1) * 16 + ln) * 24 + g * 8];
      }
      f32x4 z = {0.f, 0.f, 0.f, 0.f};
      f32x4 r0 = __builtin_amdgcn_mfma_f32_16x16x32_bf16(bw0, a1v, z, 0, 0, 0);
      f32x4 r1 = __builtin_amdgcn_mfma_f32_16x16x32_bf16(bw1, a1v, z, 0, 0, 0);
#pragma unroll
      for (int reg = 0; reg < 4; ++reg) {
        a2[kk][reg] = (short)f2bf(fmaxf(r0[reg], 0.f));
        a2[kk][4 + reg] = (short)f2bf(fmaxf(r1[reg], 0.f));
      }
    }

    // ---- per-j: G2 (a2 @ w2T global) + G4 (pa @ langT_s) + combine
#pragma unroll
    for (int j = 0; j < 4; ++j) {
      int nt = h * 4 + j;
      f32x4 ro = {b2v[j], b2v[j], b2v[j], b2v[j]};
#pragma unroll
      for (int kk = 0; kk < 4; ++kk) {
        short8 bw =
            *(const short8*)&w2T_bf[(size_t)(nt * 16 + ln) * 128 + kk * 32 + g * 8];
        ro = __builtin_amdgcn_mfma_f32_16x16x32_bf16(a2[kk], bw, ro, 0, 0, 0);
      }
      f32x4 iv = {0.f, 0.f, 0.f, 0.f};
      short8 bl = *(const short8*)&langT_s[(nt * 16 + ln) * 40 + g * 8];
      iv = __builtin_amdgcn_mfma_f32_16x16x32_bf16(pa, bl, iv, 0, 0, 0);
#pragma unroll
      for (int reg = 0; reg < 4; ++reg) {
        float fv = fbase[(size_t)nbrC[reg] * D_ + nt * 16 + ln];
        o[j][reg] += fv * iv[reg] * ro[reg];
      }
    }
  }

  // ---- cross-wave reduction (q2 partner pairs) ----
  __syncthreads();  // all tile work done; arena free for reuse
  float* R = (float*)arena;  // 8 x [64 rows][stride 20] f32 (padded banks)
  {
    float* Rw = R + w * 1280;
#pragma unroll
    for (int j = 0; j < 4; ++j)
      *(f32x4*)&Rw[(j * 16 + ln) * 20 + g * 4] = o[j];
  }
  __syncthreads();
  {
    int wp = og * 4 + h * 2;  // partner pair base (q2 = 0,1)
    float vs[2][4];
#pragma unroll
    for (int t = 0; t < 2; ++t) {
      int j = q2 * 2 + t;
      int col = (h * 4 + j) * 16 + ln;
      f32x4 sum = *(f32x4*)&R[wp * 1280 + (j * 16 + ln) * 20 + g * 4];
      sum += *(f32x4*)&R[(wp + 1) * 1280 + (j * 16 + ln) * 20 + g * 4];
#pragma unroll
      for (int reg = 0; reg < 4; ++reg) {
        int obj = og * 16 + g * 4 + reg;
        float v = sum[reg] + f_out[(size_t)(sn0 + obj) * D_ + col];
        outp[(size_t)(sn0 + obj) * D_ + col] = v;
        vs[t][reg] = v;
      }
    }
#pragma unroll
    for (int reg = 0; reg < 4; ++reg) {
      float sv = vs[0][reg] + vs[1][reg];
      sv += __shfl_xor(sv, 1);
      sv += __shfl_xor(sv, 2);
      sv += __shfl_xor(sv, 4);
      sv += __shfl_xor(sv, 8);
      if (ln == 0) atomicAdd(&score_s[og * 16 + g * 4 + reg], sv);
    }
  }
  __syncthreads();
  if (tid < CH_) score[sn0 + tid] = score_s[tid];
}

extern "C" void kernel_launch(void* const* d_in, const int* in_sizes, int n_in,
                              void* d_out, int out_size, void* d_ws,
                              size_t ws_size, hipStream_t stream) {
  const float* feat = (const float*)d_in[0];
  const float* coord = (const float*)d_in[1];
  const float* lang_feat = (const float*)d_in[2];
  const int* lang_len = (const int*)d_in[3];
  const float* rel_w1 = (const float*)d_in[4];
  const float* rel_b1 = (const float*)d_in[5];
  const float* rel_w2 = (const float*)d_in[6];
  const float* rel_b2 = (const float*)d_in[7];
  const float* lang_w1 = (const float*)d_in[8];
  const float* lang_b1 = (const float*)d_in[9];
  const float* lang_w2 = (const float*)d_in[10];
  const float* lang_b2 = (const float*)d_in[11];
  const float* feat_w1 = (const float*)d_in[12];
  const float* feat_b1 = (const float*)d_in[13];
  const float* feat_w2 = (const float*)d_in[14];
  const float* feat_b2 = (const float*)d_in[15];

  char* ws = (char*)d_ws;
  unsigned short* lang_bf = (unsigned short*)(ws);                  // 512 KB
  unsigned short* langT_bf = (unsigned short*)(ws + 524288);        // 512 KB
  float* f_out = (float*)(ws + 1048576);                            // 8 MB
  unsigned short* f_bf = (unsigned short*)(ws + 9437184);           // 4 MB
  int* idx = (int*)(ws + 13631488);                                 // ~1.1 MB
  unsigned short* w2T_bf = (unsigned short*)(ws + 14745600);        // 32 KB
  unsigned short* w1T_bf = (unsigned short*)(ws + 14778368);        // 4 KB
  unsigned short* fw1T_bf = (unsigned short*)(ws + 14782464);       // 32 KB
  unsigned short* fw2T_bf = (unsigned short*)(ws + 14815232);       // 32 KB
  unsigned short* lw1T_bf = (unsigned short*)(ws + 14848000);       // 64 KB
  unsigned short* lw2T_bf = (unsigned short*)(ws + 14913536);       // 32 KB

  float* out = (float*)d_out;
  float* score = out + (size_t)S_ * N_ * D_;

  tar_prep_kernel<<<dim3(128), dim3(256), 0, stream>>>(
      rel_w1, rel_b1, rel_w2, feat_w1, feat_w2, lang_w1, lang_w2, w1T_bf,
      w2T_bf, fw1T_bf, fw2T_bf, lw1T_bf, lw2T_bf);
  tar_prologue<<<dim3(KNN_NB + LANG_NB + FM_NB), dim3(256), 0, stream>>>(
      coord, idx, lang_feat, lw1T_bf, lang_b1, lw2T_bf, lang_b2, lang_bf,
      langT_bf, feat, fw1T_bf, feat_b1, fw2T_bf, feat_b2, f_out, f_bf);
  tar_main_mfma<<<dim3(S_ * (N_ / CH_)), dim3(512), 0, stream>>>(
      f_out, f_bf, lang_bf, langT_bf, idx, coord, w1T_bf, w2T_bf, rel_b2,
      lang_len, out, score);
}

// Round 18
// 103.965 us; speedup vs baseline: 1.8137x; 1.0589x over previous
//
#include <hip/hip_runtime.h>
#include <math.h>

#define S_ 64
#define N_ 256
#define L_ 32
#define D_ 128
#define LID_ 256
#define K1_ 17
#define CH_ 32    // objects per main block
#define NW_ 8     // waves per main block

typedef __attribute__((ext_vector_type(8))) short short8;
typedef __attribute__((ext_vector_type(4))) float f32x4;

__device__ __forceinline__ unsigned short f2bf(float f) {
  unsigned int u = __float_as_uint(f);
  u += 0x7fffu + ((u >> 16) & 1u);
  return (unsigned short)(u >> 16);
}
// NOTE (round-12): no inline-asm cvt_pk -- scheduler barrier, ILP collapse.
// NOTE (round-14): o[8] dedup spills at the 128-VGPR cap.
// NOTE (round-15): KNN fused into main = serial low-occupancy prefix (+41us).
// NOTE (round-17): sentence-major XCD swizzle: FETCH 56->7.5MB, main -6%.

// K-slot permutations (MFMA K-axis is order-agnostic as long as A and B agree):
// lang tokens: slot(t) = 8*((t&15)>>2) + 4*(t>>4) + (t&3)
// rel hidden : slot(h) = 32*(h>>5) + 8*((h&15)>>2) + 4*((h>>4)&1) + (h&3)

// ---------------------------------------------------------------- weight prep
__global__ __launch_bounds__(256) void tar_prep_kernel(
    const float* __restrict__ rw1, const float* __restrict__ rb1,
    const float* __restrict__ rw2, const float* __restrict__ fw1,
    const float* __restrict__ fw2, const float* __restrict__ lw1,
    const float* __restrict__ lw2, unsigned short* __restrict__ w1T,
    unsigned short* __restrict__ w2T, unsigned short* __restrict__ fw1T,
    unsigned short* __restrict__ fw2T, unsigned short* __restrict__ lw1T,
    unsigned short* __restrict__ lw2T) {
  int t = blockIdx.x * 256 + threadIdx.x;  // 0..32767
  {
    int k = t >> 7, n = t & 127;  // k 0..255 (lang layer1 K=256)
    lw1T[(size_t)n * 256 + k] = f2bf(lw1[(size_t)k * 128 + n]);
  }
  if (t < 16384) {
    int k = t >> 7, n = t & 127;
    int slot =
        32 * (k >> 5) + 8 * ((k & 15) >> 2) + 4 * ((k >> 4) & 1) + (k & 3);
    w2T[(size_t)n * 128 + slot] = f2bf(rw2[(size_t)k * 128 + n]);
    fw1T[(size_t)n * 128 + k] = f2bf(fw1[(size_t)k * 128 + n]);
    fw2T[(size_t)n * 128 + k] = f2bf(fw2[(size_t)k * 128 + n]);
    lw2T[(size_t)n * 128 + k] = f2bf(lw2[(size_t)k * 128 + n]);
  }
  if (t < 2048) {
    int n2 = t >> 4, k2 = t & 15;
    unsigned short v = 0;
    if (k2 < 10) v = f2bf(rw1[(size_t)k2 * 128 + n2]);
    else if (k2 == 10) v = f2bf(rb1[n2]);  // bias slot (rel10 slot10 == 1.0)
    w1T[(size_t)n2 * 16 + k2] = v;
  }
}

// ---------------------------------------------------------------- fused prologue
// roles: [0,1024) knn | [1024,1056) lang MLP (MFMA) | [1056,1312) feat MLP
#define KNN_NB 1024
#define LANG_NB 32
#define FM_NB 256
__global__ __launch_bounds__(256, 4) void tar_prologue(
    const float* __restrict__ coord, int* __restrict__ idx_out,
    const float* __restrict__ lx, const unsigned short* __restrict__ lw1T,
    const float* __restrict__ lb1, const unsigned short* __restrict__ lw2T,
    const float* __restrict__ lb2, unsigned short* __restrict__ lang_bf,
    unsigned short* __restrict__ langT_bf, const float* __restrict__ fx,
    const unsigned short* __restrict__ fw1T, const float* __restrict__ fb1,
    const unsigned short* __restrict__ fw2T, const float* __restrict__ fb2,
    float* __restrict__ f_out, unsigned short* __restrict__ f_bf) {
  __shared__ __align__(16) char uarena[34816];
  int bid = blockIdx.x;
  int tid = threadIdx.x;

  if (bid < KNN_NB) {
    // ---- KNN: block = 16 objects of ONE sentence; coords staged in LDS.
    float* cs_lds = (float*)uarena;  // [768]
    int s = bid >> 4;
    const float* cs = coord + (size_t)s * N_ * 3;
    for (int i = tid; i < 768; i += 256) cs_lds[i] = cs[i];
    __syncthreads();
    int wv = tid >> 6, l = tid & 63, grp = l >> 4, ln16 = l & 15;
    int obj = bid * 16 + wv * 4 + grp;  // 0..16383
    int n = obj & 255;
    float cx = cs_lds[n * 3 + 0], cy = cs_lds[n * 3 + 1],
          cz = cs_lds[n * 3 + 2];
    unsigned kd[16];
#pragma unroll
    for (int q = 0; q < 16; ++q) {
      int j = ln16 + q * 16;
      float dx = cs_lds[j * 3 + 0] - cx;
      float dy = cs_lds[j * 3 + 1] - cy;
      float dz = cs_lds[j * 3 + 2] - cz;
      kd[q] = __float_as_uint(dx * dx + dy * dy + dz * dz);
    }
    for (int k = 0; k < K1_; ++k) {
      unsigned m = kd[0];
#pragma unroll
      for (int q = 1; q < 16; ++q) m = min(m, kd[q]);
      int bq = 0;
#pragma unroll
      for (int q = 15; q >= 0; --q)
        if (kd[q] == m) bq = q;  // lowest q on tie -> lowest j
      int bj = ln16 + bq * 16;
      unsigned bm = m;
#pragma unroll
      for (int off = 1; off <= 8; off <<= 1) {
        unsigned om = __shfl_xor(bm, off);
        int oj = __shfl_xor(bj, off);
        if (om < bm || (om == bm && oj < bj)) { bm = om; bj = oj; }
      }
#pragma unroll
      for (int q = 0; q < 16; ++q)
        if (ln16 + q * 16 == bj) kd[q] = 0xFFFFFFFFu;
      if (ln16 == 0) idx_out[(size_t)obj * K1_ + k] = bj;
    }
  } else if (bid < KNN_NB + LANG_NB) {
    // ---- lang MLP via MFMA: 64 rows/block, K=256 layer1.
    //      h overlaid onto x_s after a1 fragments are register-resident.
    unsigned short* x_s = (unsigned short*)uarena;  // [64][264] (33792 B)
    unsigned short* h_s = (unsigned short*)uarena;  // overlay: 4x[16][136]
    int base = (bid - KNN_NB) * 64;
    int w = tid >> 6, l = tid & 63, g = l >> 4, ln = l & 15;
    for (int i = tid; i < 64 * 64; i += 256) {
      int row = i >> 6, c4 = (i & 63) * 4;
      float4 v = *(const float4*)&lx[(size_t)(base + row) * LID_ + c4];
      unsigned short* dst = &x_s[row * 264 + c4];
      dst[0] = f2bf(v.x); dst[1] = f2bf(v.y);
      dst[2] = f2bf(v.z); dst[3] = f2bf(v.w);
    }
    __syncthreads();
    float b1v[8], b2v[8];
#pragma unroll
    for (int nt = 0; nt < 8; ++nt) {
      b1v[nt] = lb1[nt * 16 + ln];
      b2v[nt] = lb2[nt * 16 + ln];
    }
    short8 a1[8];
#pragma unroll
    for (int kk = 0; kk < 8; ++kk)
      a1[kk] = *(const short8*)&x_s[(w * 16 + ln) * 264 + kk * 32 + g * 8];
    __syncthreads();  // all x_s reads done -> safe to overlay h
    unsigned short* hw = &h_s[w * 16 * 136];
#pragma unroll
    for (int nt = 0; nt < 8; ++nt) {
      f32x4 acc = {b1v[nt], b1v[nt], b1v[nt], b1v[nt]};
#pragma unroll
      for (int kk = 0; kk < 8; ++kk) {
        short8 bw =
            *(const short8*)&lw1T[(size_t)(nt * 16 + ln) * 256 + kk * 32 + g * 8];
        acc = __builtin_amdgcn_mfma_f32_16x16x32_bf16(a1[kk], bw, acc, 0, 0, 0);
      }
#pragma unroll
      for (int reg = 0; reg < 4; ++reg)
        hw[(g * 4 + reg) * 136 + nt * 16 + ln] = f2bf(fmaxf(acc[reg], 0.f));
    }
    short8 a2[4];
#pragma unroll
    for (int kk = 0; kk < 4; ++kk)
      a2[kk] = *(const short8*)&hw[ln * 136 + kk * 32 + g * 8];
#pragma unroll
    for (int nt = 0; nt < 8; ++nt) {
      f32x4 acc = {b2v[nt], b2v[nt], b2v[nt], b2v[nt]};
#pragma unroll
      for (int kk = 0; kk < 4; ++kk) {
        short8 bw =
            *(const short8*)&lw2T[(size_t)(nt * 16 + ln) * 128 + kk * 32 + g * 8];
        acc = __builtin_amdgcn_mfma_f32_16x16x32_bf16(a2[kk], bw, acc, 0, 0, 0);
      }
#pragma unroll
      for (int reg = 0; reg < 4; ++reg) {
        int row = base + w * 16 + g * 4 + reg;
        int col = nt * 16 + ln;
        unsigned short hb = f2bf(acc[reg]);
        lang_bf[(size_t)row * D_ + col] = hb;
        int s = row >> 5, t = row & 31;
        int slot = 8 * ((t & 15) >> 2) + 4 * (t >> 4) + (t & 3);
        langT_bf[((size_t)s * D_ + col) * L_ + slot] = hb;
      }
    }
  } else {
    // ---- feat MLP (MFMA), 64 rows/block
    unsigned short* x_s = (unsigned short*)uarena;            // [64][136]
    unsigned short* h_s = (unsigned short*)(uarena + 17408);  // 4x[16][136]
    int base = (bid - KNN_NB - LANG_NB) * 64;
    int w = tid >> 6, l = tid & 63, g = l >> 4, ln = l & 15;
    for (int i = tid; i < 64 * 32; i += 256) {
      int row = i >> 5, c4 = (i & 31) * 4;
      float4 v = *(const float4*)&fx[(size_t)(base + row) * D_ + c4];
      unsigned short* dst = &x_s[row * 136 + c4];
      dst[0] = f2bf(v.x); dst[1] = f2bf(v.y);
      dst[2] = f2bf(v.z); dst[3] = f2bf(v.w);
    }
    __syncthreads();
    float b1v[8], b2v[8];
#pragma unroll
    for (int nt = 0; nt < 8; ++nt) {
      b1v[nt] = fb1[nt * 16 + ln];
      b2v[nt] = fb2[nt * 16 + ln];
    }
    short8 a1[4];
#pragma unroll
    for (int kk = 0; kk < 4; ++kk)
      a1[kk] = *(const short8*)&x_s[(w * 16 + ln) * 136 + kk * 32 + g * 8];
    unsigned short* hw = &h_s[w * 16 * 136];
#pragma unroll
    for (int nt = 0; nt < 8; ++nt) {
      f32x4 acc = {b1v[nt], b1v[nt], b1v[nt], b1v[nt]};
#pragma unroll
      for (int kk = 0; kk < 4; ++kk) {
        short8 bw =
            *(const short8*)&fw1T[(size_t)(nt * 16 + ln) * 128 + kk * 32 + g * 8];
        acc = __builtin_amdgcn_mfma_f32_16x16x32_bf16(a1[kk], bw, acc, 0, 0, 0);
      }
#pragma unroll
      for (int reg = 0; reg < 4; ++reg)
        hw[(g * 4 + reg) * 136 + nt * 16 + ln] = f2bf(fmaxf(acc[reg], 0.f));
    }
    short8 a2[4];
#pragma unroll
    for (int kk = 0; kk < 4; ++kk)
      a2[kk] = *(const short8*)&hw[ln * 136 + kk * 32 + g * 8];
#pragma unroll
    for (int nt = 0; nt < 8; ++nt) {
      f32x4 acc = {b2v[nt], b2v[nt], b2v[nt], b2v[nt]};
#pragma unroll
      for (int kk = 0; kk < 4; ++kk) {
        short8 bw =
            *(const short8*)&fw2T[(size_t)(nt * 16 + ln) * 128 + kk * 32 + g * 8];
        acc = __builtin_amdgcn_mfma_f32_16x16x32_bf16(a2[kk], bw, acc, 0, 0, 0);
      }
#pragma unroll
      for (int reg = 0; reg < 4; ++reg) {
        int row = base + w * 16 + g * 4 + reg;
        int col = nt * 16 + ln;
        f_out[(size_t)row * D_ + col] = acc[reg];
        f_bf[(size_t)row * D_ + col] = f2bf(acc[reg]);
      }
    }
  }
}

// ---------------------------------------------------------------- main MFMA
// block = (sentence, 32 objects), 8 waves = (og, h, q2). Sentence-major XCD
// swizzle (round 17). Round-18: fast-math VALU diet -- __expf (v_exp) for
// the 8 softmax exps (was OCML accurate expf, ~10-15 instrs each),
// __builtin_amdgcn_rcpf for the renorm divide, __builtin_amdgcn_sqrtf for
// dist. Builtins, NOT inline asm (round-12 lesson). absmax headroom 3.28.
__global__ __launch_bounds__(512, 2) void tar_main_mfma(
    const float* __restrict__ f_out, const unsigned short* __restrict__ f_bf,
    const unsigned short* __restrict__ lang_bf,
    const unsigned short* __restrict__ langT_bf, const int* __restrict__ idxg,
    const float* __restrict__ coord, const unsigned short* __restrict__ w1T_bf,
    const unsigned short* __restrict__ w2T_bf, const float* __restrict__ rel_b2,
    const int* __restrict__ lang_len, float* __restrict__ outp,
    float* __restrict__ score) {
  // staging: lang_s [32][136]u16 @0 (8704) | langT_s [128][40]u16 @8704
  //          (10240) | w1T_s [128][24]u16 @18944 (6144) | idx_s @25088 (2176)
  //          = 27264 B; epilogue aliases arena as R = 8x[64][20] f32 (40960)
  __shared__ __align__(16) char arena[40960];
  __shared__ float score_s[CH_];

  unsigned short* lang_s = (unsigned short*)(arena);
  unsigned short* langT_s = (unsigned short*)(arena + 8704);
  unsigned short* w1T_s = (unsigned short*)(arena + 18944);
  int* idx_s = (int*)(arena + 25088);

  int b = blockIdx.x;
  int s = b & 63;       // sentence-major decode (XCD swizzle)
  int chunk = b >> 6;   // 0..7
  int sn0 = s * N_ + chunk * CH_;
  int tid = threadIdx.x;
  int w = tid >> 6;
  int l = tid & 63;
  int g = l >> 4;
  int ln = l & 15;
  int og = w >> 2;        // object group (0/1)
  int h = (w >> 1) & 1;   // nt half: tiles h*4 .. h*4+3
  int q2 = w & 1;         // k parity
  int len = lang_len[s];

  {
    int row = tid >> 4, c0 = (tid & 15) * 8;
    *(short8*)&lang_s[row * 136 + c0] =
        *(const short8*)&lang_bf[((size_t)s * L_ + row) * D_ + c0];
  }
  {
    int row = tid >> 2, c0 = (tid & 3) * 8;
    *(short8*)&langT_s[row * 40 + c0] =
        *(const short8*)&langT_bf[((size_t)s * D_ + row) * L_ + c0];
  }
  if (tid < 256) {
    int row = tid >> 1, c0 = (tid & 1) * 8;
    *(short8*)&w1T_s[row * 24 + c0] =
        *(const short8*)&w1T_bf[(size_t)row * 16 + c0];
  }
  for (int i = tid; i < CH_ * K1_; i += 512)
    idx_s[i] = idxg[(size_t)sn0 * K1_ + i];
  if (tid < CH_) score_s[tid] = 0.f;
  __syncthreads();

  float b2v[4];
#pragma unroll
  for (int j = 0; j < 4; ++j) b2v[j] = rel_b2[(h * 4 + j) * 16 + ln];

  f32x4 o[4];
#pragma unroll
  for (int j = 0; j < 4; ++j) o[j] = (f32x4){0.f, 0.f, 0.f, 0.f};

  int objA = og * 16 + ln;  // this lane's obj (B-row / column owner)
  const float* fbase = &f_out[(size_t)s * N_ * D_];
  const float* cA = coord + (size_t)(sn0 + objA) * 3;
  float cx = cA[0], cy = cA[1], cz = cA[2];

  for (int k = q2; k < K1_; k += 2) {
    int nbrA = idx_s[objA * K1_ + k];
    int nbrC[4];
#pragma unroll
    for (int reg = 0; reg < 4; ++reg)
      nbrC[reg] = idx_s[(og * 16 + g * 4 + reg) * K1_ + k];

    // ---- rel10 inline from coords (issued early; hides under G3)
    const float* cN = coord + (size_t)(s * N_ + nbrA) * 3;
    float nx = cN[0], ny = cN[1], nz = cN[2];
    float rx = nx - cx, ry = ny - cy, rz = nz - cz;
    float dist = __builtin_amdgcn_sqrtf(rx * rx + ry * ry + rz * rz);
    short8 a1v = {0, 0, 0, 0, 0, 0, 0, 0};
    if (g == 0) {
      a1v[0] = (short)f2bf(nx); a1v[1] = (short)f2bf(ny);
      a1v[2] = (short)f2bf(nz); a1v[3] = (short)f2bf(cx);
      a1v[4] = (short)f2bf(cy); a1v[5] = (short)f2bf(cz);
      a1v[6] = (short)f2bf(rx); a1v[7] = (short)f2bf(ry);
    } else if (g == 1) {
      a1v[0] = (short)f2bf(rz);
      a1v[1] = (short)f2bf(dist);
      a1v[2] = (short)0x3F80;  // 1.0 -> bias slot 10
    }

    const unsigned short* fArow = &f_bf[((size_t)s * N_ + nbrA) * D_];

    // ---- G3 swapped: at = lang @ f_nb^T -> C[token][obj], obj = ln
    f32x4 at0 = {0.f, 0.f, 0.f, 0.f}, at1 = {0.f, 0.f, 0.f, 0.f};
#pragma unroll
    for (int kk = 0; kk < 4; ++kk) {
      short8 fA = *(const short8*)&fArow[kk * 32 + g * 8];
      short8 bb0 = *(const short8*)&lang_s[ln * 136 + kk * 32 + g * 8];
      short8 bb1 = *(const short8*)&lang_s[(16 + ln) * 136 + kk * 32 + g * 8];
      at0 = __builtin_amdgcn_mfma_f32_16x16x32_bf16(bb0, fA, at0, 0, 0, 0);
      at1 = __builtin_amdgcn_mfma_f32_16x16x32_bf16(bb1, fA, at1, 0, 0, 0);
    }

    // ---- softmax for obj ln: tokens at0->4g+reg, at1->16+4g+reg.
    //      local over 8 + shfl_xor(16,32). ref-exact algebra, fast exp/rcp.
    float mx = fmaxf(fmaxf(fmaxf(at0[0], at0[1]), fmaxf(at0[2], at0[3])),
                     fmaxf(fmaxf(at1[0], at1[1]), fmaxf(at1[2], at1[3])));
    mx = fmaxf(mx, __shfl_xor(mx, 16));
    mx = fmaxf(mx, __shfl_xor(mx, 32));
    float e0[4], e1[4], p0[4], p1[4];
    float ss = 0.f, ms = 0.f;
#pragma unroll
    for (int reg = 0; reg < 4; ++reg) {
      e0[reg] = __expf(at0[reg] - mx);
      e1[reg] = __expf(at1[reg] - mx);
      ss += e0[reg] + e1[reg];
      p0[reg] = (4 * g + reg < len) ? e0[reg] : 0.f;
      p1[reg] = (16 + 4 * g + reg < len) ? e1[reg] : 0.f;
      ms += p0[reg] + p1[reg];
    }
    ss += __shfl_xor(ss, 16);
    ss += __shfl_xor(ss, 32);
    ms += __shfl_xor(ms, 16);
    ms += __shfl_xor(ms, 32);
    // == q/ssum / (ms/ssum + 1e-7); fast rcp (~1 ulp, headroom ample)
    float inv = __builtin_amdgcn_rcpf(ms + 1e-7f * ss);
    short8 pa;
#pragma unroll
    for (int reg = 0; reg < 4; ++reg) {
      pa[reg] = (short)f2bf(p0[reg] * inv);
      pa[4 + reg] = (short)f2bf(p1[reg] * inv);
    }

    // ---- G1 swapped: relh = w1T-chunks @ rel10 -> C[h][obj], obj = ln.
    //      relu + pack to a2 (K-slot perm matches w2T prep).
    short8 a2[4];
#pragma unroll
    for (int kk = 0; kk < 4; ++kk) {
      short8 bw0 = {0, 0, 0, 0, 0, 0, 0, 0};
      short8 bw1 = {0, 0, 0, 0, 0, 0, 0, 0};
      if (g < 2) {
        bw0 = *(const short8*)&w1T_s[((2 * kk) * 16 + ln) * 24 + g * 8];
        bw1 = *(const short8*)&w1T_s[((2 * kk + 1) * 16 + ln) * 24 + g * 8];
      }
      f32x4 z = {0.f, 0.f, 0.f, 0.f};
      f32x4 r0 = __builtin_amdgcn_mfma_f32_16x16x32_bf16(bw0, a1v, z, 0, 0, 0);
      f32x4 r1 = __builtin_amdgcn_mfma_f32_16x16x32_bf16(bw1, a1v, z, 0, 0, 0);
#pragma unroll
      for (int reg = 0; reg < 4; ++reg) {
        a2[kk][reg] = (short)f2bf(fmaxf(r0[reg], 0.f));
        a2[kk][4 + reg] = (short)f2bf(fmaxf(r1[reg], 0.f));
      }
    }

    // ---- per-j: G2 (a2 @ w2T global) + G4 (pa @ langT_s) + combine
#pragma unroll
    for (int j = 0; j < 4; ++j) {
      int nt = h * 4 + j;
      f32x4 ro = {b2v[j], b2v[j], b2v[j], b2v[j]};
#pragma unroll
      for (int kk = 0; kk < 4; ++kk) {
        short8 bw =
            *(const short8*)&w2T_bf[(size_t)(nt * 16 + ln) * 128 + kk * 32 + g * 8];
        ro = __builtin_amdgcn_mfma_f32_16x16x32_bf16(a2[kk], bw, ro, 0, 0, 0);
      }
      f32x4 iv = {0.f, 0.f, 0.f, 0.f};
      short8 bl = *(const short8*)&langT_s[(nt * 16 + ln) * 40 + g * 8];
      iv = __builtin_amdgcn_mfma_f32_16x16x32_bf16(pa, bl, iv, 0, 0, 0);
#pragma unroll
      for (int reg = 0; reg < 4; ++reg) {
        float fv = fbase[(size_t)nbrC[reg] * D_ + nt * 16 + ln];
        o[j][reg] += fv * iv[reg] * ro[reg];
      }
    }
  }

  // ---- cross-wave reduction (q2 partner pairs) ----
  __syncthreads();  // all tile work done; arena free for reuse
  float* R = (float*)arena;  // 8 x [64 rows][stride 20] f32 (padded banks)
  {
    float* Rw = R + w * 1280;
#pragma unroll
    for (int j = 0; j < 4; ++j)
      *(f32x4*)&Rw[(j * 16 + ln) * 20 + g * 4] = o[j];
  }
  __syncthreads();
  {
    int wp = og * 4 + h * 2;  // partner pair base (q2 = 0,1)
    float vs[2][4];
#pragma unroll
    for (int t = 0; t < 2; ++t) {
      int j = q2 * 2 + t;
      int col = (h * 4 + j) * 16 + ln;
      f32x4 sum = *(f32x4*)&R[wp * 1280 + (j * 16 + ln) * 20 + g * 4];
      sum += *(f32x4*)&R[(wp + 1) * 1280 + (j * 16 + ln) * 20 + g * 4];
#pragma unroll
      for (int reg = 0; reg < 4; ++reg) {
        int obj = og * 16 + g * 4 + reg;
        float v = sum[reg] + f_out[(size_t)(sn0 + obj) * D_ + col];
        outp[(size_t)(sn0 + obj) * D_ + col] = v;
        vs[t][reg] = v;
      }
    }
#pragma unroll
    for (int reg = 0; reg < 4; ++reg) {
      float sv = vs[0][reg] + vs[1][reg];
      sv += __shfl_xor(sv, 1);
      sv += __shfl_xor(sv, 2);
      sv += __shfl_xor(sv, 4);
      sv += __shfl_xor(sv, 8);
      if (ln == 0) atomicAdd(&score_s[og * 16 + g * 4 + reg], sv);
    }
  }
  __syncthreads();
  if (tid < CH_) score[sn0 + tid] = score_s[tid];
}

extern "C" void kernel_launch(void* const* d_in, const int* in_sizes, int n_in,
                              void* d_out, int out_size, void* d_ws,
                              size_t ws_size, hipStream_t stream) {
  const float* feat = (const float*)d_in[0];
  const float* coord = (const float*)d_in[1];
  const float* lang_feat = (const float*)d_in[2];
  const int* lang_len = (const int*)d_in[3];
  const float* rel_w1 = (const float*)d_in[4];
  const float* rel_b1 = (const float*)d_in[5];
  const float* rel_w2 = (const float*)d_in[6];
  const float* rel_b2 = (const float*)d_in[7];
  const float* lang_w1 = (const float*)d_in[8];
  const float* lang_b1 = (const float*)d_in[9];
  const float* lang_w2 = (const float*)d_in[10];
  const float* lang_b2 = (const float*)d_in[11];
  const float* feat_w1 = (const float*)d_in[12];
  const float* feat_b1 = (const float*)d_in[13];
  const float* feat_w2 = (const float*)d_in[14];
  const float* feat_b2 = (const float*)d_in[15];

  char* ws = (char*)d_ws;
  unsigned short* lang_bf = (unsigned short*)(ws);                  // 512 KB
  unsigned short* langT_bf = (unsigned short*)(ws + 524288);        // 512 KB
  float* f_out = (float*)(ws + 1048576);                            // 8 MB
  unsigned short* f_bf = (unsigned short*)(ws + 9437184);           // 4 MB
  int* idx = (int*)(ws + 13631488);                                 // ~1.1 MB
  unsigned short* w2T_bf = (unsigned short*)(ws + 14745600);        // 32 KB
  unsigned short* w1T_bf = (unsigned short*)(ws + 14778368);        // 4 KB
  unsigned short* fw1T_bf = (unsigned short*)(ws + 14782464);       // 32 KB
  unsigned short* fw2T_bf = (unsigned short*)(ws + 14815232);       // 32 KB
  unsigned short* lw1T_bf = (unsigned short*)(ws + 14848000);       // 64 KB
  unsigned short* lw2T_bf = (unsigned short*)(ws + 14913536);       // 32 KB

  float* out = (float*)d_out;
  float* score = out + (size_t)S_ * N_ * D_;

  tar_prep_kernel<<<dim3(128), dim3(256), 0, stream>>>(
      rel_w1, rel_b1, rel_w2, feat_w1, feat_w2, lang_w1, lang_w2, w1T_bf,
      w2T_bf, fw1T_bf, fw2T_bf, lw1T_bf, lw2T_bf);
  tar_prologue<<<dim3(KNN_NB + LANG_NB + FM_NB), dim3(256), 0, stream>>>(
      coord, idx, lang_feat, lw1T_bf, lang_b1, lw2T_bf, lang_b2, lang_bf,
      langT_bf, feat, fw1T_bf, feat_b1, fw2T_bf, feat_b2, f_out, f_bf);
  tar_main_mfma<<<dim3(S_ * (N_ / CH_)), dim3(512), 0, stream>>>(
      f_out, f_bf, lang_bf, langT_bf, idx, coord, w1T_bf, w2T_bf, rel_b2,
      lang_len, out, score);
}

// Round 19
// 103.791 us; speedup vs baseline: 1.8168x; 1.0017x over previous
//
#include <hip/hip_runtime.h>
#include <math.h>

#define S_ 64
#define N_ 256
#define L_ 32
#define D_ 128
#define LID_ 256
#define K1_ 17
#define CH_ 32    // objects per main block
#define NW_ 8     // waves per main block

typedef __attribute__((ext_vector_type(8))) short short8;
typedef __attribute__((ext_vector_type(4))) float f32x4;

__device__ __forceinline__ unsigned short f2bf(float f) {
  unsigned int u = __float_as_uint(f);
  u += 0x7fffu + ((u >> 16) & 1u);
  return (unsigned short)(u >> 16);
}
// NOTE (round-12): no inline-asm cvt_pk -- scheduler barrier, ILP collapse.
// NOTE (round-14): o[8] dedup spills at the 128-VGPR cap.
// NOTE (round-15): KNN fused into main = serial low-occupancy prefix (+41us).
// NOTE (round-17): sentence-major XCD swizzle: FETCH 56->7.5MB, main -6%.
// NOTE (round-18): __expf/rcp/sqrt builtins: main 70->63us.

// K-slot permutations (MFMA K-axis is order-agnostic as long as A and B agree):
// lang tokens: slot(t) = 8*((t&15)>>2) + 4*(t>>4) + (t&3)
// rel hidden : slot(h) = 32*(h>>5) + 8*((h&15)>>2) + 4*((h>>4)&1) + (h&3)

// ---------------------------------------------------------------- weight prep
__global__ __launch_bounds__(256) void tar_prep_kernel(
    const float* __restrict__ rw1, const float* __restrict__ rb1,
    const float* __restrict__ rw2, const float* __restrict__ fw1,
    const float* __restrict__ fw2, const float* __restrict__ lw1,
    const float* __restrict__ lw2, unsigned short* __restrict__ w1T,
    unsigned short* __restrict__ w2T, unsigned short* __restrict__ fw1T,
    unsigned short* __restrict__ fw2T, unsigned short* __restrict__ lw1T,
    unsigned short* __restrict__ lw2T) {
  int t = blockIdx.x * 256 + threadIdx.x;  // 0..32767
  {
    int k = t >> 7, n = t & 127;  // k 0..255 (lang layer1 K=256)
    lw1T[(size_t)n * 256 + k] = f2bf(lw1[(size_t)k * 128 + n]);
  }
  if (t < 16384) {
    int k = t >> 7, n = t & 127;
    int slot =
        32 * (k >> 5) + 8 * ((k & 15) >> 2) + 4 * ((k >> 4) & 1) + (k & 3);
    w2T[(size_t)n * 128 + slot] = f2bf(rw2[(size_t)k * 128 + n]);
    fw1T[(size_t)n * 128 + k] = f2bf(fw1[(size_t)k * 128 + n]);
    fw2T[(size_t)n * 128 + k] = f2bf(fw2[(size_t)k * 128 + n]);
    lw2T[(size_t)n * 128 + k] = f2bf(lw2[(size_t)k * 128 + n]);
  }
  if (t < 2048) {
    int n2 = t >> 4, k2 = t & 15;
    unsigned short v = 0;
    if (k2 < 10) v = f2bf(rw1[(size_t)k2 * 128 + n2]);
    else if (k2 == 10) v = f2bf(rb1[n2]);  // bias slot (rel10 slot10 == 1.0)
    w1T[(size_t)n2 * 16 + k2] = v;
  }
}

// ---------------------------------------------------------------- fused prologue
// roles: [0,1024) knn | [1024,1056) lang MLP (MFMA) | [1056,1312) feat MLP
#define KNN_NB 1024
#define LANG_NB 32
#define FM_NB 256
__global__ __launch_bounds__(256, 4) void tar_prologue(
    const float* __restrict__ coord, int* __restrict__ idx_out,
    const float* __restrict__ lx, const unsigned short* __restrict__ lw1T,
    const float* __restrict__ lb1, const unsigned short* __restrict__ lw2T,
    const float* __restrict__ lb2, unsigned short* __restrict__ lang_bf,
    unsigned short* __restrict__ langT_bf, const float* __restrict__ fx,
    const unsigned short* __restrict__ fw1T, const float* __restrict__ fb1,
    const unsigned short* __restrict__ fw2T, const float* __restrict__ fb2,
    float* __restrict__ f_out, unsigned short* __restrict__ f_bf) {
  __shared__ __align__(16) char uarena[34816];
  int bid = blockIdx.x;
  int tid = threadIdx.x;

  if (bid < KNN_NB) {
    // ---- KNN: block = 16 objects of ONE sentence; coords staged in LDS.
    //      Round-19: tie-break scan tree-ified (depth 16 -> 4): the serial
    //      priority chain was ~64 dependent cycles per selection round.
    float* cs_lds = (float*)uarena;  // [768]
    int s = bid >> 4;
    const float* cs = coord + (size_t)s * N_ * 3;
    for (int i = tid; i < 768; i += 256) cs_lds[i] = cs[i];
    __syncthreads();
    int wv = tid >> 6, l = tid & 63, grp = l >> 4, ln16 = l & 15;
    int obj = bid * 16 + wv * 4 + grp;  // 0..16383
    int n = obj & 255;
    float cx = cs_lds[n * 3 + 0], cy = cs_lds[n * 3 + 1],
          cz = cs_lds[n * 3 + 2];
    unsigned kd[16];
#pragma unroll
    for (int q = 0; q < 16; ++q) {
      int j = ln16 + q * 16;
      float dx = cs_lds[j * 3 + 0] - cx;
      float dy = cs_lds[j * 3 + 1] - cy;
      float dz = cs_lds[j * 3 + 2] - cz;
      kd[q] = __float_as_uint(dx * dx + dy * dy + dz * dz);
    }
    for (int k = 0; k < K1_; ++k) {
      // min value: depth-4 tree
      unsigned m01 = min(kd[0], kd[1]), m23 = min(kd[2], kd[3]);
      unsigned m45 = min(kd[4], kd[5]), m67 = min(kd[6], kd[7]);
      unsigned m89 = min(kd[8], kd[9]), mab = min(kd[10], kd[11]);
      unsigned mcd = min(kd[12], kd[13]), mef = min(kd[14], kd[15]);
      unsigned m03 = min(m01, m23), m47 = min(m45, m67);
      unsigned m8b = min(m89, mab), mcf = min(mcd, mef);
      unsigned m = min(min(m03, m47), min(m8b, mcf));
      // lowest q with kd[q]==m: select-then-min tree (depth 4)
      unsigned sq[16];
#pragma unroll
      for (int q = 0; q < 16; ++q) sq[q] = (kd[q] == m) ? (unsigned)q : 63u;
#pragma unroll
      for (int st = 1; st < 16; st <<= 1)
#pragma unroll
        for (int q = 0; q < 16; q += 2 * st) sq[q] = min(sq[q], sq[q + st]);
      int bq = (int)sq[0];
      int bj = ln16 + bq * 16;
      unsigned bm = m;
#pragma unroll
      for (int off = 1; off <= 8; off <<= 1) {
        unsigned om = __shfl_xor(bm, off);
        int oj = __shfl_xor(bj, off);
        if (om < bm || (om == bm && oj < bj)) { bm = om; bj = oj; }
      }
#pragma unroll
      for (int q = 0; q < 16; ++q)
        if (ln16 + q * 16 == bj) kd[q] = 0xFFFFFFFFu;
      if (ln16 == 0) idx_out[(size_t)obj * K1_ + k] = bj;
    }
  } else if (bid < KNN_NB + LANG_NB) {
    // ---- lang MLP via MFMA: 64 rows/block, K=256 layer1.
    //      h overlaid onto x_s after a1 fragments are register-resident.
    unsigned short* x_s = (unsigned short*)uarena;  // [64][264] (33792 B)
    unsigned short* h_s = (unsigned short*)uarena;  // overlay: 4x[16][136]
    int base = (bid - KNN_NB) * 64;
    int w = tid >> 6, l = tid & 63, g = l >> 4, ln = l & 15;
    for (int i = tid; i < 64 * 64; i += 256) {
      int row = i >> 6, c4 = (i & 63) * 4;
      float4 v = *(const float4*)&lx[(size_t)(base + row) * LID_ + c4];
      unsigned short* dst = &x_s[row * 264 + c4];
      dst[0] = f2bf(v.x); dst[1] = f2bf(v.y);
      dst[2] = f2bf(v.z); dst[3] = f2bf(v.w);
    }
    __syncthreads();
    float b1v[8], b2v[8];
#pragma unroll
    for (int nt = 0; nt < 8; ++nt) {
      b1v[nt] = lb1[nt * 16 + ln];
      b2v[nt] = lb2[nt * 16 + ln];
    }
    short8 a1[8];
#pragma unroll
    for (int kk = 0; kk < 8; ++kk)
      a1[kk] = *(const short8*)&x_s[(w * 16 + ln) * 264 + kk * 32 + g * 8];
    __syncthreads();  // all x_s reads done -> safe to overlay h
    unsigned short* hw = &h_s[w * 16 * 136];
#pragma unroll
    for (int nt = 0; nt < 8; ++nt) {
      f32x4 acc = {b1v[nt], b1v[nt], b1v[nt], b1v[nt]};
#pragma unroll
      for (int kk = 0; kk < 8; ++kk) {
        short8 bw =
            *(const short8*)&lw1T[(size_t)(nt * 16 + ln) * 256 + kk * 32 + g * 8];
        acc = __builtin_amdgcn_mfma_f32_16x16x32_bf16(a1[kk], bw, acc, 0, 0, 0);
      }
#pragma unroll
      for (int reg = 0; reg < 4; ++reg)
        hw[(g * 4 + reg) * 136 + nt * 16 + ln] = f2bf(fmaxf(acc[reg], 0.f));
    }
    short8 a2[4];
#pragma unroll
    for (int kk = 0; kk < 4; ++kk)
      a2[kk] = *(const short8*)&hw[ln * 136 + kk * 32 + g * 8];
#pragma unroll
    for (int nt = 0; nt < 8; ++nt) {
      f32x4 acc = {b2v[nt], b2v[nt], b2v[nt], b2v[nt]};
#pragma unroll
      for (int kk = 0; kk < 4; ++kk) {
        short8 bw =
            *(const short8*)&lw2T[(size_t)(nt * 16 + ln) * 128 + kk * 32 + g * 8];
        acc = __builtin_amdgcn_mfma_f32_16x16x32_bf16(a2[kk], bw, acc, 0, 0, 0);
      }
#pragma unroll
      for (int reg = 0; reg < 4; ++reg) {
        int row = base + w * 16 + g * 4 + reg;
        int col = nt * 16 + ln;
        unsigned short hb = f2bf(acc[reg]);
        lang_bf[(size_t)row * D_ + col] = hb;
        int s = row >> 5, t = row & 31;
        int slot = 8 * ((t & 15) >> 2) + 4 * (t >> 4) + (t & 3);
        langT_bf[((size_t)s * D_ + col) * L_ + slot] = hb;
      }
    }
  } else {
    // ---- feat MLP (MFMA), 64 rows/block
    unsigned short* x_s = (unsigned short*)uarena;            // [64][136]
    unsigned short* h_s = (unsigned short*)(uarena + 17408);  // 4x[16][136]
    int base = (bid - KNN_NB - LANG_NB) * 64;
    int w = tid >> 6, l = tid & 63, g = l >> 4, ln = l & 15;
    for (int i = tid; i < 64 * 32; i += 256) {
      int row = i >> 5, c4 = (i & 31) * 4;
      float4 v = *(const float4*)&fx[(size_t)(base + row) * D_ + c4];
      unsigned short* dst = &x_s[row * 136 + c4];
      dst[0] = f2bf(v.x); dst[1] = f2bf(v.y);
      dst[2] = f2bf(v.z); dst[3] = f2bf(v.w);
    }
    __syncthreads();
    float b1v[8], b2v[8];
#pragma unroll
    for (int nt = 0; nt < 8; ++nt) {
      b1v[nt] = fb1[nt * 16 + ln];
      b2v[nt] = fb2[nt * 16 + ln];
    }
    short8 a1[4];
#pragma unroll
    for (int kk = 0; kk < 4; ++kk)
      a1[kk] = *(const short8*)&x_s[(w * 16 + ln) * 136 + kk * 32 + g * 8];
    unsigned short* hw = &h_s[w * 16 * 136];
#pragma unroll
    for (int nt = 0; nt < 8; ++nt) {
      f32x4 acc = {b1v[nt], b1v[nt], b1v[nt], b1v[nt]};
#pragma unroll
      for (int kk = 0; kk < 4; ++kk) {
        short8 bw =
            *(const short8*)&fw1T[(size_t)(nt * 16 + ln) * 128 + kk * 32 + g * 8];
        acc = __builtin_amdgcn_mfma_f32_16x16x32_bf16(a1[kk], bw, acc, 0, 0, 0);
      }
#pragma unroll
      for (int reg = 0; reg < 4; ++reg)
        hw[(g * 4 + reg) * 136 + nt * 16 + ln] = f2bf(fmaxf(acc[reg], 0.f));
    }
    short8 a2[4];
#pragma unroll
    for (int kk = 0; kk < 4; ++kk)
      a2[kk] = *(const short8*)&hw[ln * 136 + kk * 32 + g * 8];
#pragma unroll
    for (int nt = 0; nt < 8; ++nt) {
      f32x4 acc = {b2v[nt], b2v[nt], b2v[nt], b2v[nt]};
#pragma unroll
      for (int kk = 0; kk < 4; ++kk) {
        short8 bw =
            *(const short8*)&fw2T[(size_t)(nt * 16 + ln) * 128 + kk * 32 + g * 8];
        acc = __builtin_amdgcn_mfma_f32_16x16x32_bf16(a2[kk], bw, acc, 0, 0, 0);
      }
#pragma unroll
      for (int reg = 0; reg < 4; ++reg) {
        int row = base + w * 16 + g * 4 + reg;
        int col = nt * 16 + ln;
        f_out[(size_t)row * D_ + col] = acc[reg];
        f_bf[(size_t)row * D_ + col] = f2bf(acc[reg]);
      }
    }
  }
}

// ---------------------------------------------------------------- main MFMA
// block = (sentence, 32 objects), 8 waves = (og, h, q2). Sentence-major XCD
// swizzle; fast exp/rcp/sqrt builtins; w2T from global; no inline asm.
__global__ __launch_bounds__(512, 2) void tar_main_mfma(
    const float* __restrict__ f_out, const unsigned short* __restrict__ f_bf,
    const unsigned short* __restrict__ lang_bf,
    const unsigned short* __restrict__ langT_bf, const int* __restrict__ idxg,
    const float* __restrict__ coord, const unsigned short* __restrict__ w1T_bf,
    const unsigned short* __restrict__ w2T_bf, const float* __restrict__ rel_b2,
    const int* __restrict__ lang_len, float* __restrict__ outp,
    float* __restrict__ score) {
  // staging: lang_s [32][136]u16 @0 (8704) | langT_s [128][40]u16 @8704
  //          (10240) | w1T_s [128][24]u16 @18944 (6144) | idx_s @25088 (2176)
  //          = 27264 B; epilogue aliases arena as R = 8x[64][20] f32 (40960)
  __shared__ __align__(16) char arena[40960];
  __shared__ float score_s[CH_];

  unsigned short* lang_s = (unsigned short*)(arena);
  unsigned short* langT_s = (unsigned short*)(arena + 8704);
  unsigned short* w1T_s = (unsigned short*)(arena + 18944);
  int* idx_s = (int*)(arena + 25088);

  int b = blockIdx.x;
  int s = b & 63;       // sentence-major decode (XCD swizzle)
  int chunk = b >> 6;   // 0..7
  int sn0 = s * N_ + chunk * CH_;
  int tid = threadIdx.x;
  int w = tid >> 6;
  int l = tid & 63;
  int g = l >> 4;
  int ln = l & 15;
  int og = w >> 2;        // object group (0/1)
  int h = (w >> 1) & 1;   // nt half: tiles h*4 .. h*4+3
  int q2 = w & 1;         // k parity
  int len = lang_len[s];

  {
    int row = tid >> 4, c0 = (tid & 15) * 8;
    *(short8*)&lang_s[row * 136 + c0] =
        *(const short8*)&lang_bf[((size_t)s * L_ + row) * D_ + c0];
  }
  {
    int row = tid >> 2, c0 = (tid & 3) * 8;
    *(short8*)&langT_s[row * 40 + c0] =
        *(const short8*)&langT_bf[((size_t)s * D_ + row) * L_ + c0];
  }
  if (tid < 256) {
    int row = tid >> 1, c0 = (tid & 1) * 8;
    *(short8*)&w1T_s[row * 24 + c0] =
        *(const short8*)&w1T_bf[(size_t)row * 16 + c0];
  }
  for (int i = tid; i < CH_ * K1_; i += 512)
    idx_s[i] = idxg[(size_t)sn0 * K1_ + i];
  if (tid < CH_) score_s[tid] = 0.f;
  __syncthreads();

  float b2v[4];
#pragma unroll
  for (int j = 0; j < 4; ++j) b2v[j] = rel_b2[(h * 4 + j) * 16 + ln];

  f32x4 o[4];
#pragma unroll
  for (int j = 0; j < 4; ++j) o[j] = (f32x4){0.f, 0.f, 0.f, 0.f};

  int objA = og * 16 + ln;  // this lane's obj (B-row / column owner)
  const float* fbase = &f_out[(size_t)s * N_ * D_];
  const float* cA = coord + (size_t)(sn0 + objA) * 3;
  float cx = cA[0], cy = cA[1], cz = cA[2];

  for (int k = q2; k < K1_; k += 2) {
    int nbrA = idx_s[objA * K1_ + k];
    int nbrC[4];
#pragma unroll
    for (int reg = 0; reg < 4; ++reg)
      nbrC[reg] = idx_s[(og * 16 + g * 4 + reg) * K1_ + k];

    // ---- rel10 inline from coords (issued early; hides under G3)
    const float* cN = coord + (size_t)(s * N_ + nbrA) * 3;
    float nx = cN[0], ny = cN[1], nz = cN[2];
    float rx = nx - cx, ry = ny - cy, rz = nz - cz;
    float dist = __builtin_amdgcn_sqrtf(rx * rx + ry * ry + rz * rz);
    short8 a1v = {0, 0, 0, 0, 0, 0, 0, 0};
    if (g == 0) {
      a1v[0] = (short)f2bf(nx); a1v[1] = (short)f2bf(ny);
      a1v[2] = (short)f2bf(nz); a1v[3] = (short)f2bf(cx);
      a1v[4] = (short)f2bf(cy); a1v[5] = (short)f2bf(cz);
      a1v[6] = (short)f2bf(rx); a1v[7] = (short)f2bf(ry);
    } else if (g == 1) {
      a1v[0] = (short)f2bf(rz);
      a1v[1] = (short)f2bf(dist);
      a1v[2] = (short)0x3F80;  // 1.0 -> bias slot 10
    }

    const unsigned short* fArow = &f_bf[((size_t)s * N_ + nbrA) * D_];

    // ---- G3 swapped: at = lang @ f_nb^T -> C[token][obj], obj = ln
    f32x4 at0 = {0.f, 0.f, 0.f, 0.f}, at1 = {0.f, 0.f, 0.f, 0.f};
#pragma unroll
    for (int kk = 0; kk < 4; ++kk) {
      short8 fA = *(const short8*)&fArow[kk * 32 + g * 8];
      short8 bb0 = *(const short8*)&lang_s[ln * 136 + kk * 32 + g * 8];
      short8 bb1 = *(const short8*)&lang_s[(16 + ln) * 136 + kk * 32 + g * 8];
      at0 = __builtin_amdgcn_mfma_f32_16x16x32_bf16(bb0, fA, at0, 0, 0, 0);
      at1 = __builtin_amdgcn_mfma_f32_16x16x32_bf16(bb1, fA, at1, 0, 0, 0);
    }

    // ---- softmax for obj ln: tokens at0->4g+reg, at1->16+4g+reg.
    //      local over 8 + shfl_xor(16,32). ref-exact algebra, fast exp/rcp.
    float mx = fmaxf(fmaxf(fmaxf(at0[0], at0[1]), fmaxf(at0[2], at0[3])),
                     fmaxf(fmaxf(at1[0], at1[1]), fmaxf(at1[2], at1[3])));
    mx = fmaxf(mx, __shfl_xor(mx, 16));
    mx = fmaxf(mx, __shfl_xor(mx, 32));
    float e0[4], e1[4], p0[4], p1[4];
    float ss = 0.f, ms = 0.f;
#pragma unroll
    for (int reg = 0; reg < 4; ++reg) {
      e0[reg] = __expf(at0[reg] - mx);
      e1[reg] = __expf(at1[reg] - mx);
      ss += e0[reg] + e1[reg];
      p0[reg] = (4 * g + reg < len) ? e0[reg] : 0.f;
      p1[reg] = (16 + 4 * g + reg < len) ? e1[reg] : 0.f;
      ms += p0[reg] + p1[reg];
    }
    ss += __shfl_xor(ss, 16);
    ss += __shfl_xor(ss, 32);
    ms += __shfl_xor(ms, 16);
    ms += __shfl_xor(ms, 32);
    // == q/ssum / (ms/ssum + 1e-7); fast rcp (~1 ulp, headroom ample)
    float inv = __builtin_amdgcn_rcpf(ms + 1e-7f * ss);
    short8 pa;
#pragma unroll
    for (int reg = 0; reg < 4; ++reg) {
      pa[reg] = (short)f2bf(p0[reg] * inv);
      pa[4 + reg] = (short)f2bf(p1[reg] * inv);
    }

    // ---- G1 swapped: relh = w1T-chunks @ rel10 -> C[h][obj], obj = ln.
    //      relu + pack to a2 (K-slot perm matches w2T prep).
    short8 a2[4];
#pragma unroll
    for (int kk = 0; kk < 4; ++kk) {
      short8 bw0 = {0, 0, 0, 0, 0, 0, 0, 0};
      short8 bw1 = {0, 0, 0, 0, 0, 0, 0, 0};
      if (g < 2) {
        bw0 = *(const short8*)&w1T_s[((2 * kk) * 16 + ln) * 24 + g * 8];
        bw1 = *(const short8*)&w1T_s[((2 * kk + 1) * 16 + ln) * 24 + g * 8];
      }
      f32x4 z = {0.f, 0.f, 0.f, 0.f};
      f32x4 r0 = __builtin_amdgcn_mfma_f32_16x16x32_bf16(bw0, a1v, z, 0, 0, 0);
      f32x4 r1 = __builtin_amdgcn_mfma_f32_16x16x32_bf16(bw1, a1v, z, 0, 0, 0);
#pragma unroll
      for (int reg = 0; reg < 4; ++reg) {
        a2[kk][reg] = (short)f2bf(fmaxf(r0[reg], 0.f));
        a2[kk][4 + reg] = (short)f2bf(fmaxf(r1[reg], 0.f));
      }
    }

    // ---- per-j: G2 (a2 @ w2T global) + G4 (pa @ langT_s) + combine
#pragma unroll
    for (int j = 0; j < 4; ++j) {
      int nt = h * 4 + j;
      f32x4 ro = {b2v[j], b2v[j], b2v[j], b2v[j]};
#pragma unroll
      for (int kk = 0; kk < 4; ++kk) {
        short8 bw =
            *(const short8*)&w2T_bf[(size_t)(nt * 16 + ln) * 128 + kk * 32 + g * 8];
        ro = __builtin_amdgcn_mfma_f32_16x16x32_bf16(a2[kk], bw, ro, 0, 0, 0);
      }
      f32x4 iv = {0.f, 0.f, 0.f, 0.f};
      short8 bl = *(const short8*)&langT_s[(nt * 16 + ln) * 40 + g * 8];
      iv = __builtin_amdgcn_mfma_f32_16x16x32_bf16(pa, bl, iv, 0, 0, 0);
#pragma unroll
      for (int reg = 0; reg < 4; ++reg) {
        float fv = fbase[(size_t)nbrC[reg] * D_ + nt * 16 + ln];
        o[j][reg] += fv * iv[reg] * ro[reg];
      }
    }
  }

  // ---- cross-wave reduction (q2 partner pairs) ----
  __syncthreads();  // all tile work done; arena free for reuse
  float* R = (float*)arena;  // 8 x [64 rows][stride 20] f32 (padded banks)
  {
    float* Rw = R + w * 1280;
#pragma unroll
    for (int j = 0; j < 4; ++j)
      *(f32x4*)&Rw[(j * 16 + ln) * 20 + g * 4] = o[j];
  }
  __syncthreads();
  {
    int wp = og * 4 + h * 2;  // partner pair base (q2 = 0,1)
    float vs[2][4];
#pragma unroll
    for (int t = 0; t < 2; ++t) {
      int j = q2 * 2 + t;
      int col = (h * 4 + j) * 16 + ln;
      f32x4 sum = *(f32x4*)&R[wp * 1280 + (j * 16 + ln) * 20 + g * 4];
      sum += *(f32x4*)&R[(wp + 1) * 1280 + (j * 16 + ln) * 20 + g * 4];
#pragma unroll
      for (int reg = 0; reg < 4; ++reg) {
        int obj = og * 16 + g * 4 + reg;
        float v = sum[reg] + f_out[(size_t)(sn0 + obj) * D_ + col];
        outp[(size_t)(sn0 + obj) * D_ + col] = v;
        vs[t][reg] = v;
      }
    }
#pragma unroll
    for (int reg = 0; reg < 4; ++reg) {
      float sv = vs[0][reg] + vs[1][reg];
      sv += __shfl_xor(sv, 1);
      sv += __shfl_xor(sv, 2);
      sv += __shfl_xor(sv, 4);
      sv += __shfl_xor(sv, 8);
      if (ln == 0) atomicAdd(&score_s[og * 16 + g * 4 + reg], sv);
    }
  }
  __syncthreads();
  if (tid < CH_) score[sn0 + tid] = score_s[tid];
}

extern "C" void kernel_launch(void* const* d_in, const int* in_sizes, int n_in,
                              void* d_out, int out_size, void* d_ws,
                              size_t ws_size, hipStream_t stream) {
  const float* feat = (const float*)d_in[0];
  const float* coord = (const float*)d_in[1];
  const float* lang_feat = (const float*)d_in[2];
  const int* lang_len = (const int*)d_in[3];
  const float* rel_w1 = (const float*)d_in[4];
  const float* rel_b1 = (const float*)d_in[5];
  const float* rel_w2 = (const float*)d_in[6];
  const float* rel_b2 = (const float*)d_in[7];
  const float* lang_w1 = (const float*)d_in[8];
  const float* lang_b1 = (const float*)d_in[9];
  const float* lang_w2 = (const float*)d_in[10];
  const float* lang_b2 = (const float*)d_in[11];
  const float* feat_w1 = (const float*)d_in[12];
  const float* feat_b1 = (const float*)d_in[13];
  const float* feat_w2 = (const float*)d_in[14];
  const float* feat_b2 = (const float*)d_in[15];

  char* ws = (char*)d_ws;
  unsigned short* lang_bf = (unsigned short*)(ws);                  // 512 KB
  unsigned short* langT_bf = (unsigned short*)(ws + 524288);        // 512 KB
  float* f_out = (float*)(ws + 1048576);                            // 8 MB
  unsigned short* f_bf = (unsigned short*)(ws + 9437184);           // 4 MB
  int* idx = (int*)(ws + 13631488);                                 // ~1.1 MB
  unsigned short* w2T_bf = (unsigned short*)(ws + 14745600);        // 32 KB
  unsigned short* w1T_bf = (unsigned short*)(ws + 14778368);        // 4 KB
  unsigned short* fw1T_bf = (unsigned short*)(ws + 14782464);       // 32 KB
  unsigned short* fw2T_bf = (unsigned short*)(ws + 14815232);       // 32 KB
  unsigned short* lw1T_bf = (unsigned short*)(ws + 14848000);       // 64 KB
  unsigned short* lw2T_bf = (unsigned short*)(ws + 14913536);       // 32 KB

  float* out = (float*)d_out;
  float* score = out + (size_t)S_ * N_ * D_;

  tar_prep_kernel<<<dim3(128), dim3(256), 0, stream>>>(
      rel_w1, rel_b1, rel_w2, feat_w1, feat_w2, lang_w1, lang_w2, w1T_bf,
      w2T_bf, fw1T_bf, fw2T_bf, lw1T_bf, lw2T_bf);
  tar_prologue<<<dim3(KNN_NB + LANG_NB + FM_NB), dim3(256), 0, stream>>>(
      coord, idx, lang_feat, lw1T_bf, lang_b1, lw2T_bf, lang_b2, lang_bf,
      langT_bf, feat, fw1T_bf, feat_b1, fw2T_bf, feat_b2, f_out, f_bf);
  tar_main_mfma<<<dim3(S_ * (N_ / CH_)), dim3(512), 0, stream>>>(
      f_out, f_bf, lang_bf, langT_bf, idx, coord, w1T_bf, w2T_bf, rel_b2,
      lang_len, out, score);
}